// Round 1
// 243.951 us; speedup vs baseline: 1.3204x; 1.3204x over previous
//
#include <hip/hip_runtime.h>

#define D 64  // feature dim for all layers

// ---------------------------------------------------------------------------
// GEMM: out[row][j] = sum_k f(A[row][k]) * W[k][j]
//   PRE=false: f(x) = x
//   PRE=true : f(x) = relu(x + bpre[k])   (bias+relu fused on the INPUT side,
//              valid because we reordered (A@X)@W -> A@(X@W))
// 256 threads = 4 rows x 64 cols. W staged in LDS.
// ---------------------------------------------------------------------------
template <bool PRE>
__global__ __launch_bounds__(256) void gemm64_kernel(
    const float* __restrict__ A, const float* __restrict__ W,
    const float* __restrict__ bpre, float* __restrict__ out, int N) {
  __shared__ float sW[D][D];   // 16 KB
  __shared__ float sB[D];
  __shared__ float sA[4][D];

  const int tj = threadIdx.x & 63;
  const int tr = threadIdx.x >> 6;

  for (int i = threadIdx.x; i < D * D; i += 256) sW[i >> 6][i & 63] = W[i];
  if (PRE && threadIdx.x < D) sB[threadIdx.x] = bpre[threadIdx.x];

  const int row = blockIdx.x * 4 + tr;
  float a = (row < N) ? A[(size_t)row * D + tj] : 0.f;
  __syncthreads();                       // sW, sB ready
  if (PRE) a = fmaxf(a + sB[tj], 0.f);
  sA[tr][tj] = a;
  __syncthreads();                       // sA ready

  float acc = 0.f;
#pragma unroll
  for (int k = 0; k < D; ++k) acc += sA[tr][k] * sW[k][tj];
  if (row < N) out[(size_t)row * D + tj] = acc;
}

// ---------------------------------------------------------------------------
// CSR-by-dst construction
// ---------------------------------------------------------------------------
__global__ __launch_bounds__(256) void hist_kernel(
    const int* __restrict__ dst, int* __restrict__ deg, int E) {
  int e = blockIdx.x * 256 + threadIdx.x;
  if (e < E) atomicAdd(&deg[dst[e]], 1);
}

// ---- device-wide exclusive scan, 3 kernels -------------------------------
// scan_part: each 256-thread block scans a 1024-element chunk (4 elems/thread)
// writing per-element exclusive-within-chunk prefixes to offs and the chunk
// total to bsums[blockIdx].
#define SCAN_CHUNK 1024
__global__ __launch_bounds__(256) void scan_part_kernel(
    const int* __restrict__ deg, int* __restrict__ offs,
    int* __restrict__ bsums, int N) {
  __shared__ int s[256];
  const int t = threadIdx.x;
  const int base = blockIdx.x * SCAN_CHUNK + t * 4;
  int v0 = 0, v1 = 0, v2 = 0, v3 = 0;
  if (base + 3 < N) {
    const int4 v = *reinterpret_cast<const int4*>(deg + base);
    v0 = v.x; v1 = v.y; v2 = v.z; v3 = v.w;
  } else {
    if (base + 0 < N) v0 = deg[base + 0];
    if (base + 1 < N) v1 = deg[base + 1];
    if (base + 2 < N) v2 = deg[base + 2];
  }
  const int tsum = v0 + v1 + v2 + v3;
  s[t] = tsum;
  __syncthreads();
  for (int off = 1; off < 256; off <<= 1) {
    int x = (t >= off) ? s[t - off] : 0;
    __syncthreads();
    s[t] += x;
    __syncthreads();
  }
  const int excl = s[t] - tsum;  // exclusive prefix of this thread's quad
  if (base + 0 < N) offs[base + 0] = excl;
  if (base + 1 < N) offs[base + 1] = excl + v0;
  if (base + 2 < N) offs[base + 2] = excl + v0 + v1;
  if (base + 3 < N) offs[base + 3] = excl + v0 + v1 + v2;
  if (t == 255) bsums[blockIdx.x] = s[255];
}

// scan_sums: single block exclusive-scans the (<=1024) chunk totals in place,
// and writes the grand total to *offsN (= offs[N]).
__global__ __launch_bounds__(1024) void scan_sums_kernel(
    int* __restrict__ bsums, int* __restrict__ offsN, int nb) {
  __shared__ int s[1024];
  const int t = threadIdx.x;
  const int v = (t < nb) ? bsums[t] : 0;
  s[t] = v;
  __syncthreads();
  for (int off = 1; off < 1024; off <<= 1) {
    int x = (t >= off) ? s[t - off] : 0;
    __syncthreads();
    s[t] += x;
    __syncthreads();
  }
  if (t < nb) bsums[t] = s[t] - v;   // exclusive chunk offsets
  if (t == nb - 1) *offsN = s[t];    // grand total
}

// scan_add: offs[i] += chunk offset; also materialize cursor = offs copy
// (replaces the D2D memcpy that fed bucket_kernel).
__global__ __launch_bounds__(256) void scan_add_kernel(
    int* __restrict__ offs, int* __restrict__ cursor,
    const int* __restrict__ bsums, int N) {
  const int i = blockIdx.x * 256 + threadIdx.x;
  if (i < N) {
    const int v = offs[i] + bsums[i >> 10];  // i / SCAN_CHUNK
    offs[i] = v;
    cursor[i] = v;
  }
}

// bucket fill: srcs_sorted / w_sorted grouped by dst (cursor starts = offs)
__global__ __launch_bounds__(256) void bucket_kernel(
    const int* __restrict__ src, const int* __restrict__ dst,
    const float* __restrict__ ew, int* __restrict__ cursor,
    int* __restrict__ srcs, float* __restrict__ wsorted, int E) {
  int e = blockIdx.x * 256 + threadIdx.x;
  if (e < E) {
    int pos = atomicAdd(&cursor[dst[e]], 1);
    srcs[pos] = src[e];
    wsorted[pos] = ew[e];
  }
}

// ---------------------------------------------------------------------------
// Gather-aggregate: out[n][lane] = (BIAS? b[lane]:0) + sum_i w_i * H[src_i][lane]
// One wave per node (lane = channel). 4 accumulators for memory-level ILP.
// ---------------------------------------------------------------------------
template <bool BIAS>
__global__ __launch_bounds__(256) void gather_agg_kernel(
    const float* __restrict__ H, const int* __restrict__ offs,
    const int* __restrict__ srcs, const float* __restrict__ ws,
    const float* __restrict__ bias, float* __restrict__ out, int N) {
  const int lane = threadIdx.x & 63;
  const int node = blockIdx.x * 4 + (threadIdx.x >> 6);
  if (node >= N) return;
  const int beg = offs[node], end = offs[node + 1];
  float a0 = 0.f, a1 = 0.f, a2 = 0.f, a3 = 0.f;
  int i = beg;
  for (; i + 4 <= end; i += 4) {
    int s0 = srcs[i], s1 = srcs[i + 1], s2 = srcs[i + 2], s3 = srcs[i + 3];
    float w0 = ws[i], w1 = ws[i + 1], w2 = ws[i + 2], w3 = ws[i + 3];
    a0 += w0 * H[(size_t)s0 * D + lane];
    a1 += w1 * H[(size_t)s1 * D + lane];
    a2 += w2 * H[(size_t)s2 * D + lane];
    a3 += w3 * H[(size_t)s3 * D + lane];
  }
  for (; i < end; ++i) a0 += ws[i] * H[(size_t)srcs[i] * D + lane];
  float acc = (a0 + a1) + (a2 + a3);
  if (BIAS) acc += bias[lane];
  out[(size_t)node * D + lane] = acc;
}

// ---------------------- fallback (atomic scatter) path ---------------------
__global__ __launch_bounds__(256) void scatter_kernel(
    const float* __restrict__ H, const float* __restrict__ ew,
    const int* __restrict__ src, const int* __restrict__ dst,
    float* __restrict__ out, int nEdges) {
  const int tid = blockIdx.x * 256 + threadIdx.x;
  const int e = tid >> 4;
  if (e >= nEdges) return;
  const int c = (tid & 15) * 4;
  const float w = ew[e];
  const float4 v = *reinterpret_cast<const float4*>(H + (size_t)src[e] * D + c);
  float* o = out + (size_t)dst[e] * D + c;
  atomicAdd(o + 0, w * v.x);
  atomicAdd(o + 1, w * v.y);
  atomicAdd(o + 2, w * v.z);
  atomicAdd(o + 3, w * v.w);
}

__global__ __launch_bounds__(256) void fill_bias_kernel(
    float* __restrict__ out, const float* __restrict__ b, int total) {
  int i = blockIdx.x * 256 + threadIdx.x;
  if (i < total) out[i] = b[i & 63];
}

// ---------------------------------------------------------------------------
extern "C" void kernel_launch(void* const* d_in, const int* in_sizes, int n_in,
                              void* d_out, int out_size, void* d_ws,
                              size_t ws_size, hipStream_t stream) {
  const float* X  = (const float*)d_in[0];
  const float* ew = (const float*)d_in[1];
  const float* W1 = (const float*)d_in[2];
  const float* b1 = (const float*)d_in[3];
  const float* W2 = (const float*)d_in[4];
  const float* b2 = (const float*)d_in[5];
  const int*   ei = (const int*)d_in[6];

  const int N = in_sizes[0] / D;   // 50000
  const int E = in_sizes[6] / 2;   // 800000
  const int* src = ei;
  const int* dst = ei + E;
  float* out = (float*)d_out;

  // workspace layout
  char* ws = (char*)d_ws;
  float* buf0 = (float*)ws;                 ws += (size_t)N * D * 4;
  float* buf1 = (float*)ws;                 ws += (size_t)N * D * 4;
  const size_t baseBytes = (size_t)(ws - (char*)d_ws);
  int*   offs   = (int*)ws;                 ws += (size_t)(N + 1) * 4;
  int*   cursor = (int*)ws;                 ws += (size_t)N * 4;
  int*   srcsS  = (int*)ws;                 ws += (size_t)E * 4;
  float* wS     = (float*)ws;               ws += (size_t)E * 4;
  const size_t needBytes = (size_t)(ws - (char*)d_ws);

  // CSR-build scratch aliases buf0 (dead until the first gemm writes it,
  // and all kernels are stream-ordered).
  int* deg   = (int*)buf0;                 // N ints
  int* bsums = (int*)buf0 + N;             // nb ints

  const int gemmBlocks = (N + 3) / 4;
  const int edgeBlocks = (E + 255) / 256;
  const int nb = (N + SCAN_CHUNK - 1) / SCAN_CHUNK;   // 49 (<=1024 required)

  if (ws_size >= needBytes) {
    // ---- CSR build: hist -> 3-kernel device-wide scan -> bucket ----
    hipMemsetAsync(deg, 0, (size_t)N * 4, stream);
    hist_kernel<<<edgeBlocks, 256, 0, stream>>>(dst, deg, E);
    scan_part_kernel<<<nb, 256, 0, stream>>>(deg, offs, bsums, N);
    scan_sums_kernel<<<1, 1024, 0, stream>>>(bsums, offs + N, nb);
    scan_add_kernel<<<(N + 255) / 256, 256, 0, stream>>>(offs, cursor, bsums, N);
    bucket_kernel<<<edgeBlocks, 256, 0, stream>>>(src, dst, ew, cursor, srcsS, wS, E);

    // ---- pipeline ----
    gemm64_kernel<false><<<gemmBlocks, 256, 0, stream>>>(X, W1, nullptr, buf0, N);
    gather_agg_kernel<false><<<gemmBlocks, 256, 0, stream>>>(buf0, offs, srcsS, wS, nullptr, buf1, N);
    gemm64_kernel<true><<<gemmBlocks, 256, 0, stream>>>(buf1, W2, b1, buf0, N);
    gather_agg_kernel<true><<<gemmBlocks, 256, 0, stream>>>(buf0, offs, srcsS, wS, b2, out, N);
  } else if (ws_size >= baseBytes) {
    // ---- fallback: atomic scatter (slow but correct) ----
    const int scatBlocks = (E * 16 + 255) / 256;
    const int fillBlocks = (N * D + 255) / 256;
    gemm64_kernel<false><<<gemmBlocks, 256, 0, stream>>>(X, W1, nullptr, buf0, N);
    hipMemsetAsync(buf1, 0, (size_t)N * D * 4, stream);
    scatter_kernel<<<scatBlocks, 256, 0, stream>>>(buf0, ew, src, dst, buf1, E);
    gemm64_kernel<true><<<gemmBlocks, 256, 0, stream>>>(buf1, W2, b1, buf0, N);
    fill_bias_kernel<<<fillBlocks, 256, 0, stream>>>(out, b2, N * D);
    scatter_kernel<<<scatBlocks, 256, 0, stream>>>(buf0, ew, src, dst, out, E);
  }
}

// Round 2
// 239.856 us; speedup vs baseline: 1.3430x; 1.0171x over previous
//
#include <hip/hip_runtime.h>

#define D 64  // feature dim for all layers

// ---------------------------------------------------------------------------
// GEMM: out[row][j] = sum_k f(A[row][k]) * W[k][j]
//   PRE=false: f(x) = x
//   PRE=true : f(x) = relu(x + bpre[k])   (bias+relu fused on the INPUT side,
//              valid because we reordered (A@X)@W -> A@(X@W))
// 256 threads = 4 rows x 64 cols. W staged in LDS.
// ---------------------------------------------------------------------------
template <bool PRE>
__global__ __launch_bounds__(256) void gemm64_kernel(
    const float* __restrict__ A, const float* __restrict__ W,
    const float* __restrict__ bpre, float* __restrict__ out, int N) {
  __shared__ float sW[D][D];   // 16 KB
  __shared__ float sB[D];
  __shared__ float sA[4][D];

  const int tj = threadIdx.x & 63;
  const int tr = threadIdx.x >> 6;

  for (int i = threadIdx.x; i < D * D; i += 256) sW[i >> 6][i & 63] = W[i];
  if (PRE && threadIdx.x < D) sB[threadIdx.x] = bpre[threadIdx.x];

  const int row = blockIdx.x * 4 + tr;
  float a = (row < N) ? A[(size_t)row * D + tj] : 0.f;
  __syncthreads();                       // sW, sB ready
  if (PRE) a = fmaxf(a + sB[tj], 0.f);
  sA[tr][tj] = a;
  __syncthreads();                       // sA ready

  float acc = 0.f;
#pragma unroll
  for (int k = 0; k < D; ++k) acc += sA[tr][k] * sW[k][tj];
  if (row < N) out[(size_t)row * D + tj] = acc;
}

// ---------------------------------------------------------------------------
// CSR-by-dst construction
// ---------------------------------------------------------------------------
__global__ __launch_bounds__(256) void hist_kernel(
    const int* __restrict__ dst, int* __restrict__ deg, int E) {
  int e = blockIdx.x * 256 + threadIdx.x;
  if (e < E) atomicAdd(&deg[dst[e]], 1);
}

// ---- device-wide exclusive scan, 3 kernels -------------------------------
#define SCAN_CHUNK 1024
__global__ __launch_bounds__(256) void scan_part_kernel(
    const int* __restrict__ deg, int* __restrict__ offs,
    int* __restrict__ bsums, int N) {
  __shared__ int s[256];
  const int t = threadIdx.x;
  const int base = blockIdx.x * SCAN_CHUNK + t * 4;
  int v0 = 0, v1 = 0, v2 = 0, v3 = 0;
  if (base + 3 < N) {
    const int4 v = *reinterpret_cast<const int4*>(deg + base);
    v0 = v.x; v1 = v.y; v2 = v.z; v3 = v.w;
  } else {
    if (base + 0 < N) v0 = deg[base + 0];
    if (base + 1 < N) v1 = deg[base + 1];
    if (base + 2 < N) v2 = deg[base + 2];
  }
  const int tsum = v0 + v1 + v2 + v3;
  s[t] = tsum;
  __syncthreads();
  for (int off = 1; off < 256; off <<= 1) {
    int x = (t >= off) ? s[t - off] : 0;
    __syncthreads();
    s[t] += x;
    __syncthreads();
  }
  const int excl = s[t] - tsum;  // exclusive prefix of this thread's quad
  if (base + 0 < N) offs[base + 0] = excl;
  if (base + 1 < N) offs[base + 1] = excl + v0;
  if (base + 2 < N) offs[base + 2] = excl + v0 + v1;
  if (base + 3 < N) offs[base + 3] = excl + v0 + v1 + v2;
  if (t == 255) bsums[blockIdx.x] = s[255];
}

// scan_sums: single block exclusive-scans the (<=1024) chunk totals in place,
// and writes the grand total to *offsN (= offs[N]).
__global__ __launch_bounds__(1024) void scan_sums_kernel(
    int* __restrict__ bsums, int* __restrict__ offsN, int nb) {
  __shared__ int s[1024];
  const int t = threadIdx.x;
  const int v = (t < nb) ? bsums[t] : 0;
  s[t] = v;
  __syncthreads();
  for (int off = 1; off < 1024; off <<= 1) {
    int x = (t >= off) ? s[t - off] : 0;
    __syncthreads();
    s[t] += x;
    __syncthreads();
  }
  if (t < nb) bsums[t] = s[t] - v;   // exclusive chunk offsets
  if (t == nb - 1) *offsN = s[t];    // grand total
}

// scan_add: offs[i] += chunk offset; also materialize cursor = offs copy
__global__ __launch_bounds__(256) void scan_add_kernel(
    int* __restrict__ offs, int* __restrict__ cursor,
    const int* __restrict__ bsums, int N) {
  const int i = blockIdx.x * 256 + threadIdx.x;
  if (i < N) {
    const int v = offs[i] + bsums[i >> 10];  // i / SCAN_CHUNK
    offs[i] = v;
    cursor[i] = v;
  }
}

// bucket fill: (src, weight) pairs grouped by dst (cursor starts = offs).
// Single 8B store per edge instead of 2x4B into two arrays: halves the
// number of randomly-dirtied cache lines (write-allocate traffic).
__global__ __launch_bounds__(256) void bucket_kernel(
    const int* __restrict__ src, const int* __restrict__ dst,
    const float* __restrict__ ew, int* __restrict__ cursor,
    int2* __restrict__ pairs, int E) {
  int e = blockIdx.x * 256 + threadIdx.x;
  if (e < E) {
    const int s = src[e];
    const float w = ew[e];
    int pos = atomicAdd(&cursor[dst[e]], 1);
    pairs[pos] = make_int2(s, __float_as_int(w));
  }
}

// ---------------------------------------------------------------------------
// Gather-aggregate: out[n][lane] = (BIAS? b[lane]:0) + sum_i w_i * H[src_i][lane]
// One wave per node (lane = channel). 4 accumulators for memory-level ILP.
// ---------------------------------------------------------------------------
template <bool BIAS>
__global__ __launch_bounds__(256) void gather_agg_kernel(
    const float* __restrict__ H, const int* __restrict__ offs,
    const int2* __restrict__ pairs,
    const float* __restrict__ bias, float* __restrict__ out, int N) {
  const int lane = threadIdx.x & 63;
  const int node = blockIdx.x * 4 + (threadIdx.x >> 6);
  if (node >= N) return;
  const int beg = offs[node], end = offs[node + 1];
  float a0 = 0.f, a1 = 0.f, a2 = 0.f, a3 = 0.f;
  int i = beg;
  for (; i + 4 <= end; i += 4) {
    const int2 p0 = pairs[i], p1 = pairs[i + 1], p2 = pairs[i + 2], p3 = pairs[i + 3];
    a0 += __int_as_float(p0.y) * H[(size_t)p0.x * D + lane];
    a1 += __int_as_float(p1.y) * H[(size_t)p1.x * D + lane];
    a2 += __int_as_float(p2.y) * H[(size_t)p2.x * D + lane];
    a3 += __int_as_float(p3.y) * H[(size_t)p3.x * D + lane];
  }
  for (; i < end; ++i) {
    const int2 p = pairs[i];
    a0 += __int_as_float(p.y) * H[(size_t)p.x * D + lane];
  }
  float acc = (a0 + a1) + (a2 + a3);
  if (BIAS) acc += bias[lane];
  out[(size_t)node * D + lane] = acc;
}

// ---------------------- fallback (atomic scatter) path ---------------------
__global__ __launch_bounds__(256) void scatter_kernel(
    const float* __restrict__ H, const float* __restrict__ ew,
    const int* __restrict__ src, const int* __restrict__ dst,
    float* __restrict__ out, int nEdges) {
  const int tid = blockIdx.x * 256 + threadIdx.x;
  const int e = tid >> 4;
  if (e >= nEdges) return;
  const int c = (tid & 15) * 4;
  const float w = ew[e];
  const float4 v = *reinterpret_cast<const float4*>(H + (size_t)src[e] * D + c);
  float* o = out + (size_t)dst[e] * D + c;
  atomicAdd(o + 0, w * v.x);
  atomicAdd(o + 1, w * v.y);
  atomicAdd(o + 2, w * v.z);
  atomicAdd(o + 3, w * v.w);
}

__global__ __launch_bounds__(256) void fill_bias_kernel(
    float* __restrict__ out, const float* __restrict__ b, int total) {
  int i = blockIdx.x * 256 + threadIdx.x;
  if (i < total) out[i] = b[i & 63];
}

// ---------------------------------------------------------------------------
extern "C" void kernel_launch(void* const* d_in, const int* in_sizes, int n_in,
                              void* d_out, int out_size, void* d_ws,
                              size_t ws_size, hipStream_t stream) {
  const float* X  = (const float*)d_in[0];
  const float* ew = (const float*)d_in[1];
  const float* W1 = (const float*)d_in[2];
  const float* b1 = (const float*)d_in[3];
  const float* W2 = (const float*)d_in[4];
  const float* b2 = (const float*)d_in[5];
  const int*   ei = (const int*)d_in[6];

  const int N = in_sizes[0] / D;   // 50000
  const int E = in_sizes[6] / 2;   // 800000
  const int* src = ei;
  const int* dst = ei + E;
  float* out = (float*)d_out;

  // workspace layout (pairs placed right after buf1 -> 8B aligned)
  char* ws = (char*)d_ws;
  float* buf0 = (float*)ws;                 ws += (size_t)N * D * 4;
  float* buf1 = (float*)ws;                 ws += (size_t)N * D * 4;
  const size_t baseBytes = (size_t)(ws - (char*)d_ws);
  int2*  pairs  = (int2*)ws;                ws += (size_t)E * 8;
  int*   offs   = (int*)ws;                 ws += (size_t)(N + 1) * 4;
  int*   cursor = (int*)ws;                 ws += (size_t)N * 4;
  const size_t needBytes = (size_t)(ws - (char*)d_ws);

  // CSR-build scratch aliases buf0 (dead until the first gemm writes it,
  // and all kernels are stream-ordered).
  int* deg   = (int*)buf0;                 // N ints
  int* bsums = (int*)buf0 + N;             // nb ints

  const int gemmBlocks = (N + 3) / 4;
  const int edgeBlocks = (E + 255) / 256;
  const int nb = (N + SCAN_CHUNK - 1) / SCAN_CHUNK;   // 49 (<=1024 required)

  if (ws_size >= needBytes) {
    // ---- CSR build: hist -> 3-kernel device-wide scan -> bucket ----
    hipMemsetAsync(deg, 0, (size_t)N * 4, stream);
    hist_kernel<<<edgeBlocks, 256, 0, stream>>>(dst, deg, E);
    scan_part_kernel<<<nb, 256, 0, stream>>>(deg, offs, bsums, N);
    scan_sums_kernel<<<1, 1024, 0, stream>>>(bsums, offs + N, nb);
    scan_add_kernel<<<(N + 255) / 256, 256, 0, stream>>>(offs, cursor, bsums, N);
    bucket_kernel<<<edgeBlocks, 256, 0, stream>>>(src, dst, ew, cursor, pairs, E);

    // ---- pipeline ----
    gemm64_kernel<false><<<gemmBlocks, 256, 0, stream>>>(X, W1, nullptr, buf0, N);
    gather_agg_kernel<false><<<gemmBlocks, 256, 0, stream>>>(buf0, offs, pairs, nullptr, buf1, N);
    gemm64_kernel<true><<<gemmBlocks, 256, 0, stream>>>(buf1, W2, b1, buf0, N);
    gather_agg_kernel<true><<<gemmBlocks, 256, 0, stream>>>(buf0, offs, pairs, b2, out, N);
  } else if (ws_size >= baseBytes) {
    // ---- fallback: atomic scatter (slow but correct) ----
    const int scatBlocks = (E * 16 + 255) / 256;
    const int fillBlocks = (N * D + 255) / 256;
    gemm64_kernel<false><<<gemmBlocks, 256, 0, stream>>>(X, W1, nullptr, buf0, N);
    hipMemsetAsync(buf1, 0, (size_t)N * D * 4, stream);
    scatter_kernel<<<scatBlocks, 256, 0, stream>>>(buf0, ew, src, dst, buf1, E);
    gemm64_kernel<true><<<gemmBlocks, 256, 0, stream>>>(buf1, W2, b1, buf0, N);
    fill_bias_kernel<<<fillBlocks, 256, 0, stream>>>(out, b2, N * D);
    scatter_kernel<<<scatBlocks, 256, 0, stream>>>(buf0, ew, src, dst, out, E);
  }
}

// Round 3
// 200.624 us; speedup vs baseline: 1.6056x; 1.1956x over previous
//
#include <hip/hip_runtime.h>

#define D 64  // feature dim for all layers

// ---------------------------------------------------------------------------
// GEMM: out[row][j] = sum_k f(A[row][k]) * W[k][j]
//   PRE=false: f(x) = x
//   PRE=true : f(x) = relu(x + bpre[k])   (bias+relu fused on the INPUT side,
//              valid because we reordered (A@X)@W -> A@(X@W))
// 256 threads = 4 rows x 64 cols. W staged in LDS.
// ---------------------------------------------------------------------------
template <bool PRE>
__global__ __launch_bounds__(256) void gemm64_kernel(
    const float* __restrict__ A, const float* __restrict__ W,
    const float* __restrict__ bpre, float* __restrict__ out, int N) {
  __shared__ float sW[D][D];   // 16 KB
  __shared__ float sB[D];
  __shared__ float sA[4][D];

  const int tj = threadIdx.x & 63;
  const int tr = threadIdx.x >> 6;

  for (int i = threadIdx.x; i < D * D; i += 256) sW[i >> 6][i & 63] = W[i];
  if (PRE && threadIdx.x < D) sB[threadIdx.x] = bpre[threadIdx.x];

  const int row = blockIdx.x * 4 + tr;
  float a = (row < N) ? A[(size_t)row * D + tj] : 0.f;
  __syncthreads();                       // sW, sB ready
  if (PRE) a = fmaxf(a + sB[tj], 0.f);
  sA[tr][tj] = a;
  __syncthreads();                       // sA ready

  float acc = 0.f;
#pragma unroll
  for (int k = 0; k < D; ++k) acc += sA[tr][k] * sW[k][tj];
  if (row < N) out[(size_t)row * D + tj] = acc;
}

// ---------------------------------------------------------------------------
// CSR-by-dst construction.
// hist: deg[] histogram AND per-edge within-bucket rank (posw) from the SAME
// atomic — the returned value is the edge's rank among same-dst edges. This
// makes the later bucket pass atomic-free (pos = offs[dst] + posw).
// ---------------------------------------------------------------------------
__global__ __launch_bounds__(256) void hist_kernel(
    const int* __restrict__ dst, int* __restrict__ deg,
    int* __restrict__ posw, int E) {
  int e = blockIdx.x * 256 + threadIdx.x;
  if (e < E) posw[e] = atomicAdd(&deg[dst[e]], 1);
}

// ---- device-wide exclusive scan, 3 kernels -------------------------------
#define SCAN_CHUNK 1024
__global__ __launch_bounds__(256) void scan_part_kernel(
    const int* __restrict__ deg, int* __restrict__ offs,
    int* __restrict__ bsums, int N) {
  __shared__ int s[256];
  const int t = threadIdx.x;
  const int base = blockIdx.x * SCAN_CHUNK + t * 4;
  int v0 = 0, v1 = 0, v2 = 0, v3 = 0;
  if (base + 3 < N) {
    const int4 v = *reinterpret_cast<const int4*>(deg + base);
    v0 = v.x; v1 = v.y; v2 = v.z; v3 = v.w;
  } else {
    if (base + 0 < N) v0 = deg[base + 0];
    if (base + 1 < N) v1 = deg[base + 1];
    if (base + 2 < N) v2 = deg[base + 2];
  }
  const int tsum = v0 + v1 + v2 + v3;
  s[t] = tsum;
  __syncthreads();
  for (int off = 1; off < 256; off <<= 1) {
    int x = (t >= off) ? s[t - off] : 0;
    __syncthreads();
    s[t] += x;
    __syncthreads();
  }
  const int excl = s[t] - tsum;  // exclusive prefix of this thread's quad
  if (base + 0 < N) offs[base + 0] = excl;
  if (base + 1 < N) offs[base + 1] = excl + v0;
  if (base + 2 < N) offs[base + 2] = excl + v0 + v1;
  if (base + 3 < N) offs[base + 3] = excl + v0 + v1 + v2;
  if (t == 255) bsums[blockIdx.x] = s[255];
}

// scan_sums: single block exclusive-scans the (<=1024) chunk totals in place,
// and writes the grand total to *offsN (= offs[N]).
__global__ __launch_bounds__(1024) void scan_sums_kernel(
    int* __restrict__ bsums, int* __restrict__ offsN, int nb) {
  __shared__ int s[1024];
  const int t = threadIdx.x;
  const int v = (t < nb) ? bsums[t] : 0;
  s[t] = v;
  __syncthreads();
  for (int off = 1; off < 1024; off <<= 1) {
    int x = (t >= off) ? s[t - off] : 0;
    __syncthreads();
    s[t] += x;
    __syncthreads();
  }
  if (t < nb) bsums[t] = s[t] - v;   // exclusive chunk offsets
  if (t == nb - 1) *offsN = s[t];    // grand total
}

// scan_add: offs[i] += chunk offset (no cursor copy needed anymore)
__global__ __launch_bounds__(256) void scan_add_kernel(
    int* __restrict__ offs, const int* __restrict__ bsums, int N) {
  const int i = blockIdx.x * 256 + threadIdx.x;
  if (i < N) offs[i] += bsums[i >> 10];  // i / SCAN_CHUNK
}

// bucket fill: (src, weight) pairs grouped by dst — ATOMIC-FREE.
// pos = offs[dst] + rank recorded during hist. Coalesced reads + one random
// 8B store per edge (stores shown not to be the limiter in R1->R2 A/B).
__global__ __launch_bounds__(256) void bucket_kernel(
    const int* __restrict__ src, const int* __restrict__ dst,
    const float* __restrict__ ew, const int* __restrict__ offs,
    const int* __restrict__ posw, int2* __restrict__ pairs, int E) {
  int e = blockIdx.x * 256 + threadIdx.x;
  if (e < E) {
    const int pos = offs[dst[e]] + posw[e];
    pairs[pos] = make_int2(src[e], __float_as_int(ew[e]));
  }
}

// ---------------------------------------------------------------------------
// Gather-aggregate: out[n][lane] = (BIAS? b[lane]:0) + sum_i w_i * H[src_i][lane]
// One wave per node (lane = channel). 4 accumulators for memory-level ILP.
// ---------------------------------------------------------------------------
template <bool BIAS>
__global__ __launch_bounds__(256) void gather_agg_kernel(
    const float* __restrict__ H, const int* __restrict__ offs,
    const int2* __restrict__ pairs,
    const float* __restrict__ bias, float* __restrict__ out, int N) {
  const int lane = threadIdx.x & 63;
  const int node = blockIdx.x * 4 + (threadIdx.x >> 6);
  if (node >= N) return;
  const int beg = offs[node], end = offs[node + 1];
  float a0 = 0.f, a1 = 0.f, a2 = 0.f, a3 = 0.f;
  int i = beg;
  for (; i + 4 <= end; i += 4) {
    const int2 p0 = pairs[i], p1 = pairs[i + 1], p2 = pairs[i + 2], p3 = pairs[i + 3];
    a0 += __int_as_float(p0.y) * H[(size_t)p0.x * D + lane];
    a1 += __int_as_float(p1.y) * H[(size_t)p1.x * D + lane];
    a2 += __int_as_float(p2.y) * H[(size_t)p2.x * D + lane];
    a3 += __int_as_float(p3.y) * H[(size_t)p3.x * D + lane];
  }
  for (; i < end; ++i) {
    const int2 p = pairs[i];
    a0 += __int_as_float(p.y) * H[(size_t)p.x * D + lane];
  }
  float acc = (a0 + a1) + (a2 + a3);
  if (BIAS) acc += bias[lane];
  out[(size_t)node * D + lane] = acc;
}

// ---------------------- fallback (atomic scatter) path ---------------------
__global__ __launch_bounds__(256) void scatter_kernel(
    const float* __restrict__ H, const float* __restrict__ ew,
    const int* __restrict__ src, const int* __restrict__ dst,
    float* __restrict__ out, int nEdges) {
  const int tid = blockIdx.x * 256 + threadIdx.x;
  const int e = tid >> 4;
  if (e >= nEdges) return;
  const int c = (tid & 15) * 4;
  const float w = ew[e];
  const float4 v = *reinterpret_cast<const float4*>(H + (size_t)src[e] * D + c);
  float* o = out + (size_t)dst[e] * D + c;
  atomicAdd(o + 0, w * v.x);
  atomicAdd(o + 1, w * v.y);
  atomicAdd(o + 2, w * v.z);
  atomicAdd(o + 3, w * v.w);
}

__global__ __launch_bounds__(256) void fill_bias_kernel(
    float* __restrict__ out, const float* __restrict__ b, int total) {
  int i = blockIdx.x * 256 + threadIdx.x;
  if (i < total) out[i] = b[i & 63];
}

// ---------------------------------------------------------------------------
extern "C" void kernel_launch(void* const* d_in, const int* in_sizes, int n_in,
                              void* d_out, int out_size, void* d_ws,
                              size_t ws_size, hipStream_t stream) {
  const float* X  = (const float*)d_in[0];
  const float* ew = (const float*)d_in[1];
  const float* W1 = (const float*)d_in[2];
  const float* b1 = (const float*)d_in[3];
  const float* W2 = (const float*)d_in[4];
  const float* b2 = (const float*)d_in[5];
  const int*   ei = (const int*)d_in[6];

  const int N = in_sizes[0] / D;   // 50000
  const int E = in_sizes[6] / 2;   // 800000
  const int* src = ei;
  const int* dst = ei + E;
  float* out = (float*)d_out;

  // workspace layout (pairs placed right after buf1 -> 8B aligned)
  char* ws = (char*)d_ws;
  float* buf0 = (float*)ws;                 ws += (size_t)N * D * 4;
  float* buf1 = (float*)ws;                 ws += (size_t)N * D * 4;
  const size_t baseBytes = (size_t)(ws - (char*)d_ws);
  int2*  pairs  = (int2*)ws;                ws += (size_t)E * 8;
  int*   offs   = (int*)ws;                 ws += (size_t)(N + 1) * 4;
  const size_t needBytes = (size_t)(ws - (char*)d_ws);

  // CSR-build scratch aliases buf0/buf1 (both dead until gemm1/gather1 write
  // them, and all kernels are stream-ordered):
  //   deg   : buf0[0..N)        (read until scan_part; gemm1 runs later)
  //   bsums : buf0[N..N+nb)
  //   posw  : buf1[0..E)        (read until bucket; gather1 writes buf1 later)
  int* deg   = (int*)buf0;
  int* bsums = (int*)buf0 + N;
  int* posw  = (int*)buf1;

  const int gemmBlocks = (N + 3) / 4;
  const int edgeBlocks = (E + 255) / 256;
  const int nb = (N + SCAN_CHUNK - 1) / SCAN_CHUNK;   // 49 (<=1024 required)

  if (ws_size >= needBytes) {
    // ---- CSR build: hist(+rank) -> 3-kernel scan -> atomic-free bucket ----
    hipMemsetAsync(deg, 0, (size_t)N * 4, stream);
    hist_kernel<<<edgeBlocks, 256, 0, stream>>>(dst, deg, posw, E);
    scan_part_kernel<<<nb, 256, 0, stream>>>(deg, offs, bsums, N);
    scan_sums_kernel<<<1, 1024, 0, stream>>>(bsums, offs + N, nb);
    scan_add_kernel<<<(N + 255) / 256, 256, 0, stream>>>(offs, bsums, N);
    bucket_kernel<<<edgeBlocks, 256, 0, stream>>>(src, dst, ew, offs, posw, pairs, E);

    // ---- pipeline ----
    gemm64_kernel<false><<<gemmBlocks, 256, 0, stream>>>(X, W1, nullptr, buf0, N);
    gather_agg_kernel<false><<<gemmBlocks, 256, 0, stream>>>(buf0, offs, pairs, nullptr, buf1, N);
    gemm64_kernel<true><<<gemmBlocks, 256, 0, stream>>>(buf1, W2, b1, buf0, N);
    gather_agg_kernel<true><<<gemmBlocks, 256, 0, stream>>>(buf0, offs, pairs, b2, out, N);
  } else if (ws_size >= baseBytes) {
    // ---- fallback: atomic scatter (slow but correct) ----
    const int scatBlocks = (E * 16 + 255) / 256;
    const int fillBlocks = (N * D + 255) / 256;
    gemm64_kernel<false><<<gemmBlocks, 256, 0, stream>>>(X, W1, nullptr, buf0, N);
    hipMemsetAsync(buf1, 0, (size_t)N * D * 4, stream);
    scatter_kernel<<<scatBlocks, 256, 0, stream>>>(buf0, ew, src, dst, buf1, E);
    gemm64_kernel<true><<<gemmBlocks, 256, 0, stream>>>(buf1, W2, b1, buf0, N);
    fill_bias_kernel<<<fillBlocks, 256, 0, stream>>>(out, b2, N * D);
    scatter_kernel<<<scatBlocks, 256, 0, stream>>>(buf0, ew, src, dst, out, E);
  }
}

// Round 4
// 170.168 us; speedup vs baseline: 1.8930x; 1.1790x over previous
//
#include <hip/hip_runtime.h>

#define D 64  // feature dim for all layers

// ---------------------------------------------------------------------------
// GEMM: out[row][j] = sum_k f(A[row][k]) * W[k][j]
//   PRE=false: f(x) = x
//   PRE=true : f(x) = relu(x + bpre[k])
// 256 threads = 4 rows x 64 cols. W staged in LDS.
// ---------------------------------------------------------------------------
template <bool PRE>
__global__ __launch_bounds__(256) void gemm64_kernel(
    const float* __restrict__ A, const float* __restrict__ W,
    const float* __restrict__ bpre, float* __restrict__ out, int N) {
  __shared__ float sW[D][D];   // 16 KB
  __shared__ float sB[D];
  __shared__ float sA[4][D];

  const int tj = threadIdx.x & 63;
  const int tr = threadIdx.x >> 6;

  for (int i = threadIdx.x; i < D * D; i += 256) sW[i >> 6][i & 63] = W[i];
  if (PRE && threadIdx.x < D) sB[threadIdx.x] = bpre[threadIdx.x];

  const int row = blockIdx.x * 4 + tr;
  float a = (row < N) ? A[(size_t)row * D + tj] : 0.f;
  __syncthreads();                       // sW, sB ready
  if (PRE) a = fmaxf(a + sB[tj], 0.f);
  sA[tr][tj] = a;
  __syncthreads();                       // sA ready

  float acc = 0.f;
#pragma unroll
  for (int k = 0; k < D; ++k) acc += sA[tr][k] * sW[k][tj];
  if (row < N) out[(size_t)row * D + tj] = acc;
}

// ---------------------------------------------------------------------------
// Generic CSR build (N > 65536 path): hist(+rank) atomics
// ---------------------------------------------------------------------------
__global__ __launch_bounds__(256) void hist_kernel(
    const int* __restrict__ dst, int* __restrict__ deg,
    int* __restrict__ posw, int E) {
  int e = blockIdx.x * 256 + threadIdx.x;
  if (e < E) posw[e] = atomicAdd(&deg[dst[e]], 1);
}

// ---- device-wide exclusive scan, 3 kernels -------------------------------
#define SCAN_CHUNK 1024
__global__ __launch_bounds__(256) void scan_part_kernel(
    const int* __restrict__ deg, int* __restrict__ offs,
    int* __restrict__ bsums, int N) {
  __shared__ int s[256];
  const int t = threadIdx.x;
  const int base = blockIdx.x * SCAN_CHUNK + t * 4;
  int v0 = 0, v1 = 0, v2 = 0, v3 = 0;
  if (base + 3 < N) {
    const int4 v = *reinterpret_cast<const int4*>(deg + base);
    v0 = v.x; v1 = v.y; v2 = v.z; v3 = v.w;
  } else {
    if (base + 0 < N) v0 = deg[base + 0];
    if (base + 1 < N) v1 = deg[base + 1];
    if (base + 2 < N) v2 = deg[base + 2];
  }
  const int tsum = v0 + v1 + v2 + v3;
  s[t] = tsum;
  __syncthreads();
  for (int off = 1; off < 256; off <<= 1) {
    int x = (t >= off) ? s[t - off] : 0;
    __syncthreads();
    s[t] += x;
    __syncthreads();
  }
  const int excl = s[t] - tsum;
  if (base + 0 < N) offs[base + 0] = excl;
  if (base + 1 < N) offs[base + 1] = excl + v0;
  if (base + 2 < N) offs[base + 2] = excl + v0 + v1;
  if (base + 3 < N) offs[base + 3] = excl + v0 + v1 + v2;
  if (t == 255) bsums[blockIdx.x] = s[255];
}

__global__ __launch_bounds__(1024) void scan_sums_kernel(
    int* __restrict__ bsums, int* __restrict__ offsN, int nb) {
  __shared__ int s[1024];
  const int t = threadIdx.x;
  const int v = (t < nb) ? bsums[t] : 0;
  s[t] = v;
  __syncthreads();
  for (int off = 1; off < 1024; off <<= 1) {
    int x = (t >= off) ? s[t - off] : 0;
    __syncthreads();
    s[t] += x;
    __syncthreads();
  }
  if (t < nb) bsums[t] = s[t] - v;   // exclusive chunk offsets
  if (t == nb - 1) *offsN = s[t];    // grand total
}

__global__ __launch_bounds__(256) void scan_add_kernel(
    int* __restrict__ offs, const int* __restrict__ bsums, int N) {
  const int i = blockIdx.x * 256 + threadIdx.x;
  if (i < N) offs[i] += bsums[i >> 10];  // i / SCAN_CHUNK
}

// generic-path bucket fill (atomic-free via posw ranks)
__global__ __launch_bounds__(256) void bucket_kernel(
    const int* __restrict__ src, const int* __restrict__ dst,
    const float* __restrict__ ew, const int* __restrict__ offs,
    const int* __restrict__ posw, int2* __restrict__ pairs, int E) {
  int e = blockIdx.x * 256 + threadIdx.x;
  if (e < E) {
    const int pos = offs[dst[e]] + posw[e];
    pairs[pos] = make_int2(src[e], __float_as_int(ew[e]));
  }
}

// ---------------------------------------------------------------------------
// Radix CSR build (N <= 65536): NO global atomics anywhere.
// Level 1: bucket by dst>>8 (256 coarse buckets, LDS hist + LDS cursors).
// Level 2: per-coarse-bucket LDS counting sort by dst&255 -> exact dst
//          grouping; emits pairs AND offs directly.
// ---------------------------------------------------------------------------
#define NB 256   // level-1 blocks
#define RB 256   // radix bins

// countsT[bin*NB + blk] = #edges with dst>>8==bin in block blk's range
__global__ __launch_bounds__(256) void p1_hist_kernel(
    const int* __restrict__ dst, int* __restrict__ countsT, int E, int epb) {
  __shared__ int h[RB];
  const int t = threadIdx.x;
  h[t] = 0;
  __syncthreads();
  const int base = blockIdx.x * epb;
  const int lim = min(base + epb, E);
  for (int i = base + t; i < lim; i += 256) atomicAdd(&h[dst[i] >> 8], 1);
  __syncthreads();
  countsT[t * NB + blockIdx.x] = h[t];
}

// scatter into coarse buckets; record packs (dst | src<<16, wbits)
__global__ __launch_bounds__(256) void p1_scatter_kernel(
    const int* __restrict__ src, const int* __restrict__ dst,
    const float* __restrict__ ew, const int* __restrict__ SC,
    int2* __restrict__ tmp, int E, int epb) {
  __shared__ int cur[RB];
  const int t = threadIdx.x;
  cur[t] = SC[t * NB + blockIdx.x];
  __syncthreads();
  const int base = blockIdx.x * epb;
  const int lim = min(base + epb, E);
  for (int i = base + t; i < lim; i += 256) {
    const int d = dst[i];
    const unsigned s = (unsigned)src[i];
    const float w = ew[i];
    const int pos = atomicAdd(&cur[d >> 8], 1);   // LDS atomic
    tmp[pos] = make_int2((int)((unsigned)d | (s << 16)), __float_as_int(w));
  }
}

// one block per coarse bucket b: counting-sort its segment by dst&255,
// write (src, w) pairs and offs[] for nodes b*256 .. min(b*256+255, N)
__global__ __launch_bounds__(256) void p2_kernel(
    const int2* __restrict__ tmp, const int* __restrict__ SC,
    int* __restrict__ offs, int2* __restrict__ pairs, int N, int E) {
  __shared__ int h[RB];
  __shared__ int s[RB];
  __shared__ int cur[RB];
  const int t = threadIdx.x;
  const int b = blockIdx.x;
  const int segBeg = SC[b * RB];
  const int segEnd = SC[min((b + 1) * RB, NB * RB)];  // SC[65536] == E

  h[t] = 0;
  __syncthreads();
  for (int i = segBeg + t; i < segEnd; i += 256)
    atomicAdd(&h[tmp[i].x & 255], 1);
  __syncthreads();

  // exclusive scan of h over 256 bins
  const int v = h[t];
  s[t] = v;
  __syncthreads();
  for (int off = 1; off < 256; off <<= 1) {
    int x = (t >= off) ? s[t - off] : 0;
    __syncthreads();
    s[t] += x;
    __syncthreads();
  }
  const int excl = s[t] - v;
  cur[t] = segBeg + excl;
  const int node = b * RB + t;
  if (node <= N) offs[node] = segBeg + excl;  // offs[N] lands here too
  __syncthreads();

  for (int i = segBeg + t; i < segEnd; i += 256) {
    const int2 r = tmp[i];
    const int lo = r.x & 255;
    const int pos = atomicAdd(&cur[lo], 1);    // LDS atomic
    pairs[pos] = make_int2((int)(((unsigned)r.x) >> 16), r.y);
  }
}

// ---------------------------------------------------------------------------
// Gather-aggregate: out[n][lane] = (BIAS? b[lane]:0) + sum_i w_i * H[src_i][lane]
// One wave per node (lane = channel). 4 accumulators for memory-level ILP.
// ---------------------------------------------------------------------------
template <bool BIAS>
__global__ __launch_bounds__(256) void gather_agg_kernel(
    const float* __restrict__ H, const int* __restrict__ offs,
    const int2* __restrict__ pairs,
    const float* __restrict__ bias, float* __restrict__ out, int N) {
  const int lane = threadIdx.x & 63;
  const int node = blockIdx.x * 4 + (threadIdx.x >> 6);
  if (node >= N) return;
  const int beg = offs[node], end = offs[node + 1];
  float a0 = 0.f, a1 = 0.f, a2 = 0.f, a3 = 0.f;
  int i = beg;
  for (; i + 4 <= end; i += 4) {
    const int2 p0 = pairs[i], p1 = pairs[i + 1], p2 = pairs[i + 2], p3 = pairs[i + 3];
    a0 += __int_as_float(p0.y) * H[(size_t)p0.x * D + lane];
    a1 += __int_as_float(p1.y) * H[(size_t)p1.x * D + lane];
    a2 += __int_as_float(p2.y) * H[(size_t)p2.x * D + lane];
    a3 += __int_as_float(p3.y) * H[(size_t)p3.x * D + lane];
  }
  for (; i < end; ++i) {
    const int2 p = pairs[i];
    a0 += __int_as_float(p.y) * H[(size_t)p.x * D + lane];
  }
  float acc = (a0 + a1) + (a2 + a3);
  if (BIAS) acc += bias[lane];
  out[(size_t)node * D + lane] = acc;
}

// ---------------------- fallback (atomic scatter) path ---------------------
__global__ __launch_bounds__(256) void scatter_kernel(
    const float* __restrict__ H, const float* __restrict__ ew,
    const int* __restrict__ src, const int* __restrict__ dst,
    float* __restrict__ out, int nEdges) {
  const int tid = blockIdx.x * 256 + threadIdx.x;
  const int e = tid >> 4;
  if (e >= nEdges) return;
  const int c = (tid & 15) * 4;
  const float w = ew[e];
  const float4 v = *reinterpret_cast<const float4*>(H + (size_t)src[e] * D + c);
  float* o = out + (size_t)dst[e] * D + c;
  atomicAdd(o + 0, w * v.x);
  atomicAdd(o + 1, w * v.y);
  atomicAdd(o + 2, w * v.z);
  atomicAdd(o + 3, w * v.w);
}

__global__ __launch_bounds__(256) void fill_bias_kernel(
    float* __restrict__ out, const float* __restrict__ b, int total) {
  int i = blockIdx.x * 256 + threadIdx.x;
  if (i < total) out[i] = b[i & 63];
}

// ---------------------------------------------------------------------------
extern "C" void kernel_launch(void* const* d_in, const int* in_sizes, int n_in,
                              void* d_out, int out_size, void* d_ws,
                              size_t ws_size, hipStream_t stream) {
  const float* X  = (const float*)d_in[0];
  const float* ew = (const float*)d_in[1];
  const float* W1 = (const float*)d_in[2];
  const float* b1 = (const float*)d_in[3];
  const float* W2 = (const float*)d_in[4];
  const float* b2 = (const float*)d_in[5];
  const int*   ei = (const int*)d_in[6];

  const int N = in_sizes[0] / D;   // 50000
  const int E = in_sizes[6] / 2;   // 800000
  const int* src = ei;
  const int* dst = ei + E;
  float* out = (float*)d_out;

  // workspace layout
  char* ws = (char*)d_ws;
  float* buf0 = (float*)ws;                 ws += (size_t)N * D * 4;
  float* buf1 = (float*)ws;                 ws += (size_t)N * D * 4;
  const size_t baseBytes = (size_t)(ws - (char*)d_ws);
  int2*  pairs  = (int2*)ws;                ws += (size_t)E * 8;
  int*   offs   = (int*)ws;                 ws += (size_t)(N + 1) * 4;
  const size_t needBytes = (size_t)(ws - (char*)d_ws);

  const int gemmBlocks = (N + 3) / 4;
  const int edgeBlocks = (E + 255) / 256;

  if (ws_size >= needBytes) {
    if (N <= 65536 && (size_t)N * D * 4 >= (size_t)(2 * NB * RB + 1 + 64) * 4 &&
        (size_t)N * D * 4 >= (size_t)E * 8) {
      // ---- radix build: zero global atomics ----
      // scratch aliasing (all build kernels precede gemm/gather writes):
      //   countsT, SC, bsums -> buf0 ; tmp records -> buf1
      int*  countsT = (int*)buf0;                    // 65536
      int*  SC      = (int*)buf0 + NB * RB;          // 65537
      int*  bsums   = (int*)buf0 + 2 * NB * RB + 1;  // 64
      int2* tmp     = (int2*)buf1;                   // E records

      const int epb = (E + NB - 1) / NB;
      p1_hist_kernel<<<NB, 256, 0, stream>>>(dst, countsT, E, epb);
      scan_part_kernel<<<NB * RB / SCAN_CHUNK, 256, 0, stream>>>(countsT, SC, bsums, NB * RB);
      scan_sums_kernel<<<1, 1024, 0, stream>>>(bsums, SC + NB * RB, NB * RB / SCAN_CHUNK);
      scan_add_kernel<<<NB * RB / 256, 256, 0, stream>>>(SC, bsums, NB * RB);
      p1_scatter_kernel<<<NB, 256, 0, stream>>>(src, dst, ew, SC, tmp, E, epb);
      p2_kernel<<<RB, 256, 0, stream>>>(tmp, SC, offs, pairs, N, E);
    } else {
      // ---- generic build: hist(+rank) -> N-scan -> atomic-free bucket ----
      int* deg   = (int*)buf0;
      int* bsums = (int*)buf0 + N;
      int* posw  = (int*)buf1;
      const int nb = (N + SCAN_CHUNK - 1) / SCAN_CHUNK;
      hipMemsetAsync(deg, 0, (size_t)N * 4, stream);
      hist_kernel<<<edgeBlocks, 256, 0, stream>>>(dst, deg, posw, E);
      scan_part_kernel<<<nb, 256, 0, stream>>>(deg, offs, bsums, N);
      scan_sums_kernel<<<1, 1024, 0, stream>>>(bsums, offs + N, nb);
      scan_add_kernel<<<(N + 255) / 256, 256, 0, stream>>>(offs, bsums, N);
      bucket_kernel<<<edgeBlocks, 256, 0, stream>>>(src, dst, ew, offs, posw, pairs, E);
    }

    // ---- pipeline ----
    gemm64_kernel<false><<<gemmBlocks, 256, 0, stream>>>(X, W1, nullptr, buf0, N);
    gather_agg_kernel<false><<<gemmBlocks, 256, 0, stream>>>(buf0, offs, pairs, nullptr, buf1, N);
    gemm64_kernel<true><<<gemmBlocks, 256, 0, stream>>>(buf1, W2, b1, buf0, N);
    gather_agg_kernel<true><<<gemmBlocks, 256, 0, stream>>>(buf0, offs, pairs, b2, out, N);
  } else if (ws_size >= baseBytes) {
    // ---- fallback: atomic scatter (slow but correct) ----
    const int scatBlocks = (E * 16 + 255) / 256;
    const int fillBlocks = (N * D + 255) / 256;
    gemm64_kernel<false><<<gemmBlocks, 256, 0, stream>>>(X, W1, nullptr, buf0, N);
    hipMemsetAsync(buf1, 0, (size_t)N * D * 4, stream);
    scatter_kernel<<<scatBlocks, 256, 0, stream>>>(buf0, ew, src, dst, buf1, E);
    gemm64_kernel<true><<<gemmBlocks, 256, 0, stream>>>(buf1, W2, b1, buf0, N);
    fill_bias_kernel<<<fillBlocks, 256, 0, stream>>>(out, b2, N * D);
    scatter_kernel<<<scatBlocks, 256, 0, stream>>>(buf0, ew, src, dst, out, E);
  }
}

// Round 5
// 158.489 us; speedup vs baseline: 2.0325x; 1.0737x over previous
//
#include <hip/hip_runtime.h>

#define D 64  // feature dim for all layers

// ---------------------------------------------------------------------------
// GEMM: out = f(A) @ W, A is N x 64, W is 64 x 64.
//   PRE=false: f(x) = x ; PRE=true: f(x) = relu(x + bpre[k]) (input-side fuse)
// 64x64 tile per block, 256 threads, 4x4 outputs/thread, LDS pad 68
// (272B rows: 16B-aligned for b128, 2-way-max bank aliasing = free).
// ---------------------------------------------------------------------------
template <bool PRE>
__global__ __launch_bounds__(256) void gemm64_kernel(
    const float* __restrict__ A, const float* __restrict__ W,
    const float* __restrict__ bpre, float* __restrict__ out, int N) {
  __shared__ float sA[64][68];
  __shared__ float sW[64][68];
  const int t = threadIdx.x;
  const int rowBase = blockIdx.x * 64;

#pragma unroll
  for (int i = t * 4; i < 4096; i += 1024) {
    const int k = i >> 6, c = i & 63;
    *reinterpret_cast<float4*>(&sW[k][c]) =
        *reinterpret_cast<const float4*>(W + i);
  }
#pragma unroll
  for (int i = t * 4; i < 4096; i += 1024) {
    const int r = i >> 6, k = i & 63;
    const int row = rowBase + r;
    float4 a = make_float4(0.f, 0.f, 0.f, 0.f);
    if (row < N) a = *reinterpret_cast<const float4*>(A + (size_t)row * D + k);
    if (PRE) {
      const float4 b = *reinterpret_cast<const float4*>(bpre + k);
      a.x = fmaxf(a.x + b.x, 0.f);
      a.y = fmaxf(a.y + b.y, 0.f);
      a.z = fmaxf(a.z + b.z, 0.f);
      a.w = fmaxf(a.w + b.w, 0.f);
    }
    *reinterpret_cast<float4*>(&sA[r][k]) = a;
  }
  __syncthreads();

  const int ty = t >> 4, tx = t & 15;   // 16 row-quads x 16 col-quads
  float4 acc0 = make_float4(0.f, 0.f, 0.f, 0.f);
  float4 acc1 = make_float4(0.f, 0.f, 0.f, 0.f);
  float4 acc2 = make_float4(0.f, 0.f, 0.f, 0.f);
  float4 acc3 = make_float4(0.f, 0.f, 0.f, 0.f);

#pragma unroll
  for (int kq = 0; kq < 16; ++kq) {
    const float4 w0 = *reinterpret_cast<const float4*>(&sW[kq * 4 + 0][tx * 4]);
    const float4 w1 = *reinterpret_cast<const float4*>(&sW[kq * 4 + 1][tx * 4]);
    const float4 w2 = *reinterpret_cast<const float4*>(&sW[kq * 4 + 2][tx * 4]);
    const float4 w3 = *reinterpret_cast<const float4*>(&sW[kq * 4 + 3][tx * 4]);
    const float4 a0 = *reinterpret_cast<const float4*>(&sA[ty * 4 + 0][kq * 4]);
    const float4 a1 = *reinterpret_cast<const float4*>(&sA[ty * 4 + 1][kq * 4]);
    const float4 a2 = *reinterpret_cast<const float4*>(&sA[ty * 4 + 2][kq * 4]);
    const float4 a3 = *reinterpret_cast<const float4*>(&sA[ty * 4 + 3][kq * 4]);
#define FMA4(ACC, AV)                                                     \
    ACC.x += AV.x * w0.x + AV.y * w1.x + AV.z * w2.x + AV.w * w3.x;       \
    ACC.y += AV.x * w0.y + AV.y * w1.y + AV.z * w2.y + AV.w * w3.y;       \
    ACC.z += AV.x * w0.z + AV.y * w1.z + AV.z * w2.z + AV.w * w3.z;       \
    ACC.w += AV.x * w0.w + AV.y * w1.w + AV.z * w2.w + AV.w * w3.w;
    FMA4(acc0, a0) FMA4(acc1, a1) FMA4(acc2, a2) FMA4(acc3, a3)
#undef FMA4
  }

  const int row0 = rowBase + ty * 4;
  if (row0 + 0 < N) *reinterpret_cast<float4*>(out + (size_t)(row0 + 0) * D + tx * 4) = acc0;
  if (row0 + 1 < N) *reinterpret_cast<float4*>(out + (size_t)(row0 + 1) * D + tx * 4) = acc1;
  if (row0 + 2 < N) *reinterpret_cast<float4*>(out + (size_t)(row0 + 2) * D + tx * 4) = acc2;
  if (row0 + 3 < N) *reinterpret_cast<float4*>(out + (size_t)(row0 + 3) * D + tx * 4) = acc3;
}

// ---------------------------------------------------------------------------
// Generic CSR build (N > 65536 path): hist(+rank) atomics
// ---------------------------------------------------------------------------
__global__ __launch_bounds__(256) void hist_kernel(
    const int* __restrict__ dst, int* __restrict__ deg,
    int* __restrict__ posw, int E) {
  int e = blockIdx.x * 256 + threadIdx.x;
  if (e < E) posw[e] = atomicAdd(&deg[dst[e]], 1);
}

// ---- device-wide exclusive scan, 3 kernels -------------------------------
#define SCAN_CHUNK 1024
__global__ __launch_bounds__(256) void scan_part_kernel(
    const int* __restrict__ deg, int* __restrict__ offs,
    int* __restrict__ bsums, int N) {
  __shared__ int s[256];
  const int t = threadIdx.x;
  const int base = blockIdx.x * SCAN_CHUNK + t * 4;
  int v0 = 0, v1 = 0, v2 = 0, v3 = 0;
  if (base + 3 < N) {
    const int4 v = *reinterpret_cast<const int4*>(deg + base);
    v0 = v.x; v1 = v.y; v2 = v.z; v3 = v.w;
  } else {
    if (base + 0 < N) v0 = deg[base + 0];
    if (base + 1 < N) v1 = deg[base + 1];
    if (base + 2 < N) v2 = deg[base + 2];
  }
  const int tsum = v0 + v1 + v2 + v3;
  s[t] = tsum;
  __syncthreads();
  for (int off = 1; off < 256; off <<= 1) {
    int x = (t >= off) ? s[t - off] : 0;
    __syncthreads();
    s[t] += x;
    __syncthreads();
  }
  const int excl = s[t] - tsum;
  if (base + 0 < N) offs[base + 0] = excl;
  if (base + 1 < N) offs[base + 1] = excl + v0;
  if (base + 2 < N) offs[base + 2] = excl + v0 + v1;
  if (base + 3 < N) offs[base + 3] = excl + v0 + v1 + v2;
  if (t == 255) bsums[blockIdx.x] = s[255];
}

__global__ __launch_bounds__(1024) void scan_sums_kernel(
    int* __restrict__ bsums, int* __restrict__ offsN, int nb) {
  __shared__ int s[1024];
  const int t = threadIdx.x;
  const int v = (t < nb) ? bsums[t] : 0;
  s[t] = v;
  __syncthreads();
  for (int off = 1; off < 1024; off <<= 1) {
    int x = (t >= off) ? s[t - off] : 0;
    __syncthreads();
    s[t] += x;
    __syncthreads();
  }
  if (t < nb) bsums[t] = s[t] - v;   // exclusive chunk offsets
  if (t == nb - 1) *offsN = s[t];    // grand total
}

__global__ __launch_bounds__(256) void scan_add_kernel(
    int* __restrict__ offs, const int* __restrict__ bsums, int N) {
  const int i = blockIdx.x * 256 + threadIdx.x;
  if (i < N) offs[i] += bsums[i >> 10];
}

// generic-path bucket fill (atomic-free via posw ranks)
__global__ __launch_bounds__(256) void bucket_kernel(
    const int* __restrict__ src, const int* __restrict__ dst,
    const float* __restrict__ ew, const int* __restrict__ offs,
    const int* __restrict__ posw, int2* __restrict__ pairs, int E) {
  int e = blockIdx.x * 256 + threadIdx.x;
  if (e < E) {
    const int pos = offs[dst[e]] + posw[e];
    pairs[pos] = make_int2(src[e], __float_as_int(ew[e]));
  }
}

// ---------------------------------------------------------------------------
// Radix CSR build (N <= 65536): NO global atomics. bsums folded into readers
// (scan_add not needed on this path).
// ---------------------------------------------------------------------------
#define NB 256   // level-1 blocks
#define RB 256   // radix bins

__global__ __launch_bounds__(256) void p1_hist_kernel(
    const int* __restrict__ dst, int* __restrict__ countsT, int E, int epb) {
  __shared__ int h[RB];
  const int t = threadIdx.x;
  h[t] = 0;
  __syncthreads();
  const int base = blockIdx.x * epb;
  const int lim = min(base + epb, E);
  for (int i = base + t; i < lim; i += 256) atomicAdd(&h[dst[i] >> 8], 1);
  __syncthreads();
  countsT[t * NB + blockIdx.x] = h[t];
}

__global__ __launch_bounds__(256) void p1_scatter_kernel(
    const int* __restrict__ src, const int* __restrict__ dst,
    const float* __restrict__ ew, const int* __restrict__ SC,
    const int* __restrict__ bsums, int2* __restrict__ tmp, int E, int epb) {
  __shared__ int cur[RB];
  const int t = threadIdx.x;
  const int idx = t * NB + blockIdx.x;
  cur[t] = SC[idx] + bsums[idx >> 10];
  __syncthreads();
  const int base = blockIdx.x * epb;
  const int lim = min(base + epb, E);
  for (int i = base + t; i < lim; i += 256) {
    const int d = dst[i];
    const unsigned s = (unsigned)src[i];
    const float w = ew[i];
    const int pos = atomicAdd(&cur[d >> 8], 1);   // LDS atomic
    tmp[pos] = make_int2((int)((unsigned)d | (s << 16)), __float_as_int(w));
  }
}

__global__ __launch_bounds__(256) void p2_kernel(
    const int2* __restrict__ tmp, const int* __restrict__ SC,
    const int* __restrict__ bsums,
    int* __restrict__ offs, int2* __restrict__ pairs, int N, int E) {
  __shared__ int h[RB];
  __shared__ int s[RB];
  __shared__ int cur[RB];
  const int t = threadIdx.x;
  const int b = blockIdx.x;
  const int segBeg = SC[b * RB] + bsums[b >> 2];
  const int segEnd = (b == RB - 1) ? E : (SC[(b + 1) * RB] + bsums[(b + 1) >> 2]);

  h[t] = 0;
  __syncthreads();
  for (int i = segBeg + t; i < segEnd; i += 256)
    atomicAdd(&h[tmp[i].x & 255], 1);
  __syncthreads();

  const int v = h[t];
  s[t] = v;
  __syncthreads();
  for (int off = 1; off < 256; off <<= 1) {
    int x = (t >= off) ? s[t - off] : 0;
    __syncthreads();
    s[t] += x;
    __syncthreads();
  }
  const int excl = s[t] - v;
  cur[t] = segBeg + excl;
  const int node = b * RB + t;
  if (node <= N) offs[node] = segBeg + excl;  // offs[N] lands here too
  __syncthreads();

  for (int i = segBeg + t; i < segEnd; i += 256) {
    const int2 r = tmp[i];
    const int lo = r.x & 255;
    const int pos = atomicAdd(&cur[lo], 1);    // LDS atomic
    pairs[pos] = make_int2((int)(((unsigned)r.x) >> 16), r.y);
  }
}

// ---------------------------------------------------------------------------
// Gather-aggregate: 16 lanes per node, float4 per lane (one dwordx4 covers
// a row with 16 lanes). 4 nodes per wave, 16 nodes per block. 2-deep unroll
// -> 8 row-fetches in flight per wave.
// ---------------------------------------------------------------------------
template <bool BIAS>
__global__ __launch_bounds__(256) void gather_agg_kernel(
    const float* __restrict__ H, const int* __restrict__ offs,
    const int2* __restrict__ pairs,
    const float* __restrict__ bias, float* __restrict__ out, int N) {
  const int l4 = threadIdx.x & 15;                 // 16B chunk within row
  const int node = blockIdx.x * 16 + (threadIdx.x >> 4);
  if (node >= N) return;
  const int beg = offs[node], end = offs[node + 1];
  float4 A0 = make_float4(0.f, 0.f, 0.f, 0.f);
  float4 A1 = make_float4(0.f, 0.f, 0.f, 0.f);
  int i = beg;
  for (; i + 2 <= end; i += 2) {
    const int2 p0 = pairs[i], p1 = pairs[i + 1];
    const float4 v0 = *reinterpret_cast<const float4*>(H + (size_t)p0.x * D + l4 * 4);
    const float4 v1 = *reinterpret_cast<const float4*>(H + (size_t)p1.x * D + l4 * 4);
    const float w0 = __int_as_float(p0.y), w1 = __int_as_float(p1.y);
    A0.x += w0 * v0.x; A0.y += w0 * v0.y; A0.z += w0 * v0.z; A0.w += w0 * v0.w;
    A1.x += w1 * v1.x; A1.y += w1 * v1.y; A1.z += w1 * v1.z; A1.w += w1 * v1.w;
  }
  if (i < end) {
    const int2 p = pairs[i];
    const float4 v = *reinterpret_cast<const float4*>(H + (size_t)p.x * D + l4 * 4);
    const float w = __int_as_float(p.y);
    A0.x += w * v.x; A0.y += w * v.y; A0.z += w * v.z; A0.w += w * v.w;
  }
  float4 r;
  r.x = A0.x + A1.x; r.y = A0.y + A1.y; r.z = A0.z + A1.z; r.w = A0.w + A1.w;
  if (BIAS) {
    const float4 b = *reinterpret_cast<const float4*>(bias + l4 * 4);
    r.x += b.x; r.y += b.y; r.z += b.z; r.w += b.w;
  }
  *reinterpret_cast<float4*>(out + (size_t)node * D + l4 * 4) = r;
}

// ---------------------- fallback (atomic scatter) path ---------------------
__global__ __launch_bounds__(256) void scatter_kernel(
    const float* __restrict__ H, const float* __restrict__ ew,
    const int* __restrict__ src, const int* __restrict__ dst,
    float* __restrict__ out, int nEdges) {
  const int tid = blockIdx.x * 256 + threadIdx.x;
  const int e = tid >> 4;
  if (e >= nEdges) return;
  const int c = (tid & 15) * 4;
  const float w = ew[e];
  const float4 v = *reinterpret_cast<const float4*>(H + (size_t)src[e] * D + c);
  float* o = out + (size_t)dst[e] * D + c;
  atomicAdd(o + 0, w * v.x);
  atomicAdd(o + 1, w * v.y);
  atomicAdd(o + 2, w * v.z);
  atomicAdd(o + 3, w * v.w);
}

__global__ __launch_bounds__(256) void fill_bias_kernel(
    float* __restrict__ out, const float* __restrict__ b, int total) {
  int i = blockIdx.x * 256 + threadIdx.x;
  if (i < total) out[i] = b[i & 63];
}

// ---------------------------------------------------------------------------
extern "C" void kernel_launch(void* const* d_in, const int* in_sizes, int n_in,
                              void* d_out, int out_size, void* d_ws,
                              size_t ws_size, hipStream_t stream) {
  const float* X  = (const float*)d_in[0];
  const float* ew = (const float*)d_in[1];
  const float* W1 = (const float*)d_in[2];
  const float* b1 = (const float*)d_in[3];
  const float* W2 = (const float*)d_in[4];
  const float* b2 = (const float*)d_in[5];
  const int*   ei = (const int*)d_in[6];

  const int N = in_sizes[0] / D;   // 50000
  const int E = in_sizes[6] / 2;   // 800000
  const int* src = ei;
  const int* dst = ei + E;
  float* out = (float*)d_out;

  // workspace layout
  char* ws = (char*)d_ws;
  float* buf0 = (float*)ws;                 ws += (size_t)N * D * 4;
  float* buf1 = (float*)ws;                 ws += (size_t)N * D * 4;
  const size_t baseBytes = (size_t)(ws - (char*)d_ws);
  int2*  pairs  = (int2*)ws;                ws += (size_t)E * 8;
  int*   offs   = (int*)ws;                 ws += (size_t)(N + 1) * 4;
  const size_t needBytes = (size_t)(ws - (char*)d_ws);

  const int gemmBlocks = (N + 63) / 64;
  const int aggBlocks  = (N + 15) / 16;
  const int edgeBlocks = (E + 255) / 256;

  if (ws_size >= needBytes) {
    if (N <= 65536 && (size_t)N * D * 4 >= (size_t)(2 * NB * RB + 1 + 64) * 4 &&
        (size_t)N * D * 4 >= (size_t)E * 8) {
      // ---- radix build: zero global atomics ----
      int*  countsT = (int*)buf0;                    // 65536
      int*  SC      = (int*)buf0 + NB * RB;          // 65537
      int*  bsums   = (int*)buf0 + 2 * NB * RB + 1;  // 64
      int2* tmp     = (int2*)buf1;                   // E records

      const int epb = (E + NB - 1) / NB;
      p1_hist_kernel<<<NB, 256, 0, stream>>>(dst, countsT, E, epb);
      scan_part_kernel<<<NB * RB / SCAN_CHUNK, 256, 0, stream>>>(countsT, SC, bsums, NB * RB);
      scan_sums_kernel<<<1, 1024, 0, stream>>>(bsums, SC + NB * RB, NB * RB / SCAN_CHUNK);
      p1_scatter_kernel<<<NB, 256, 0, stream>>>(src, dst, ew, SC, bsums, tmp, E, epb);
      p2_kernel<<<RB, 256, 0, stream>>>(tmp, SC, bsums, offs, pairs, N, E);
    } else {
      // ---- generic build: hist(+rank) -> N-scan -> atomic-free bucket ----
      int* deg   = (int*)buf0;
      int* bsums = (int*)buf0 + N;
      int* posw  = (int*)buf1;
      const int nb = (N + SCAN_CHUNK - 1) / SCAN_CHUNK;
      hipMemsetAsync(deg, 0, (size_t)N * 4, stream);
      hist_kernel<<<edgeBlocks, 256, 0, stream>>>(dst, deg, posw, E);
      scan_part_kernel<<<nb, 256, 0, stream>>>(deg, offs, bsums, N);
      scan_sums_kernel<<<1, 1024, 0, stream>>>(bsums, offs + N, nb);
      scan_add_kernel<<<(N + 255) / 256, 256, 0, stream>>>(offs, bsums, N);
      bucket_kernel<<<edgeBlocks, 256, 0, stream>>>(src, dst, ew, offs, posw, pairs, E);
    }

    // ---- pipeline ----
    gemm64_kernel<false><<<gemmBlocks, 256, 0, stream>>>(X, W1, nullptr, buf0, N);
    gather_agg_kernel<false><<<aggBlocks, 256, 0, stream>>>(buf0, offs, pairs, nullptr, buf1, N);
    gemm64_kernel<true><<<gemmBlocks, 256, 0, stream>>>(buf1, W2, b1, buf0, N);
    gather_agg_kernel<true><<<aggBlocks, 256, 0, stream>>>(buf0, offs, pairs, b2, out, N);
  } else if (ws_size >= baseBytes) {
    // ---- fallback: atomic scatter (slow but correct) ----
    const int scatBlocks = (E * 16 + 255) / 256;
    const int fillBlocks = (N * D + 255) / 256;
    gemm64_kernel<false><<<gemmBlocks, 256, 0, stream>>>(X, W1, nullptr, buf0, N);
    hipMemsetAsync(buf1, 0, (size_t)N * D * 4, stream);
    scatter_kernel<<<scatBlocks, 256, 0, stream>>>(buf0, ew, src, dst, buf1, E);
    gemm64_kernel<true><<<gemmBlocks, 256, 0, stream>>>(buf1, W2, b1, buf0, N);
    fill_bias_kernel<<<fillBlocks, 256, 0, stream>>>(out, b2, N * D);
    scatter_kernel<<<scatBlocks, 256, 0, stream>>>(buf0, ew, src, dst, out, E);
  }
}

// Round 6
// 124.075 us; speedup vs baseline: 2.5962x; 1.2774x over previous
//
#include <hip/hip_runtime.h>

#define D 64  // feature dim for all layers

// ---------------------------------------------------------------------------
// GEMM: out = f(A) @ W, A is N x 64, W is 64 x 64.
//   PRE=false: f(x) = x ; PRE=true: f(x) = relu(x + bpre[k]) (input-side fuse)
// 64x64 tile per block, 256 threads, 4x4 outputs/thread, LDS pad 68.
// __launch_bounds__(256,4): force <=128 VGPR so 4 blocks/CU stay resident
// (R5 post-mortem: full unroll ballooned to 256 VGPR -> 9% occupancy,
//  latency-bound at 55us; the kernel's roofline is ~5us).
// ---------------------------------------------------------------------------
template <bool PRE>
__global__ __launch_bounds__(256, 4) void gemm64_kernel(
    const float* __restrict__ A, const float* __restrict__ W,
    const float* __restrict__ bpre, float* __restrict__ out, int N) {
  __shared__ float sA[64][68];
  __shared__ float sW[64][68];
  const int t = threadIdx.x;
  const int rowBase = blockIdx.x * 64;

#pragma unroll
  for (int i = t * 4; i < 4096; i += 1024) {
    const int k = i >> 6, c = i & 63;
    *reinterpret_cast<float4*>(&sW[k][c]) =
        *reinterpret_cast<const float4*>(W + i);
  }
#pragma unroll
  for (int i = t * 4; i < 4096; i += 1024) {
    const int r = i >> 6, k = i & 63;
    const int row = rowBase + r;
    float4 a = make_float4(0.f, 0.f, 0.f, 0.f);
    if (row < N) a = *reinterpret_cast<const float4*>(A + (size_t)row * D + k);
    if (PRE) {
      const float4 b = *reinterpret_cast<const float4*>(bpre + k);
      a.x = fmaxf(a.x + b.x, 0.f);
      a.y = fmaxf(a.y + b.y, 0.f);
      a.z = fmaxf(a.z + b.z, 0.f);
      a.w = fmaxf(a.w + b.w, 0.f);
    }
    *reinterpret_cast<float4*>(&sA[r][k]) = a;
  }
  __syncthreads();

  const int ty = t >> 4, tx = t & 15;   // 16 row-quads x 16 col-quads
  float4 acc0 = make_float4(0.f, 0.f, 0.f, 0.f);
  float4 acc1 = make_float4(0.f, 0.f, 0.f, 0.f);
  float4 acc2 = make_float4(0.f, 0.f, 0.f, 0.f);
  float4 acc3 = make_float4(0.f, 0.f, 0.f, 0.f);

#pragma unroll 4
  for (int kq = 0; kq < 16; ++kq) {
    const float4 w0 = *reinterpret_cast<const float4*>(&sW[kq * 4 + 0][tx * 4]);
    const float4 w1 = *reinterpret_cast<const float4*>(&sW[kq * 4 + 1][tx * 4]);
    const float4 w2 = *reinterpret_cast<const float4*>(&sW[kq * 4 + 2][tx * 4]);
    const float4 w3 = *reinterpret_cast<const float4*>(&sW[kq * 4 + 3][tx * 4]);
    const float4 a0 = *reinterpret_cast<const float4*>(&sA[ty * 4 + 0][kq * 4]);
    const float4 a1 = *reinterpret_cast<const float4*>(&sA[ty * 4 + 1][kq * 4]);
    const float4 a2 = *reinterpret_cast<const float4*>(&sA[ty * 4 + 2][kq * 4]);
    const float4 a3 = *reinterpret_cast<const float4*>(&sA[ty * 4 + 3][kq * 4]);
#define FMA4(ACC, AV)                                                     \
    ACC.x += AV.x * w0.x + AV.y * w1.x + AV.z * w2.x + AV.w * w3.x;       \
    ACC.y += AV.x * w0.y + AV.y * w1.y + AV.z * w2.y + AV.w * w3.y;       \
    ACC.z += AV.x * w0.z + AV.y * w1.z + AV.z * w2.z + AV.w * w3.z;       \
    ACC.w += AV.x * w0.w + AV.y * w1.w + AV.z * w2.w + AV.w * w3.w;
    FMA4(acc0, a0) FMA4(acc1, a1) FMA4(acc2, a2) FMA4(acc3, a3)
#undef FMA4
  }

  const int row0 = rowBase + ty * 4;
  if (row0 + 0 < N) *reinterpret_cast<float4*>(out + (size_t)(row0 + 0) * D + tx * 4) = acc0;
  if (row0 + 1 < N) *reinterpret_cast<float4*>(out + (size_t)(row0 + 1) * D + tx * 4) = acc1;
  if (row0 + 2 < N) *reinterpret_cast<float4*>(out + (size_t)(row0 + 2) * D + tx * 4) = acc2;
  if (row0 + 3 < N) *reinterpret_cast<float4*>(out + (size_t)(row0 + 3) * D + tx * 4) = acc3;
}

// ---------------------------------------------------------------------------
// Generic CSR build (N > 65536 path): hist(+rank) atomics
// ---------------------------------------------------------------------------
__global__ __launch_bounds__(256) void hist_kernel(
    const int* __restrict__ dst, int* __restrict__ deg,
    int* __restrict__ posw, int E) {
  int e = blockIdx.x * 256 + threadIdx.x;
  if (e < E) posw[e] = atomicAdd(&deg[dst[e]], 1);
}

// ---- device-wide exclusive scan, 3 kernels -------------------------------
#define SCAN_CHUNK 1024
__global__ __launch_bounds__(256) void scan_part_kernel(
    const int* __restrict__ deg, int* __restrict__ offs,
    int* __restrict__ bsums, int N) {
  __shared__ int s[256];
  const int t = threadIdx.x;
  const int base = blockIdx.x * SCAN_CHUNK + t * 4;
  int v0 = 0, v1 = 0, v2 = 0, v3 = 0;
  if (base + 3 < N) {
    const int4 v = *reinterpret_cast<const int4*>(deg + base);
    v0 = v.x; v1 = v.y; v2 = v.z; v3 = v.w;
  } else {
    if (base + 0 < N) v0 = deg[base + 0];
    if (base + 1 < N) v1 = deg[base + 1];
    if (base + 2 < N) v2 = deg[base + 2];
  }
  const int tsum = v0 + v1 + v2 + v3;
  s[t] = tsum;
  __syncthreads();
  for (int off = 1; off < 256; off <<= 1) {
    int x = (t >= off) ? s[t - off] : 0;
    __syncthreads();
    s[t] += x;
    __syncthreads();
  }
  const int excl = s[t] - tsum;
  if (base + 0 < N) offs[base + 0] = excl;
  if (base + 1 < N) offs[base + 1] = excl + v0;
  if (base + 2 < N) offs[base + 2] = excl + v0 + v1;
  if (base + 3 < N) offs[base + 3] = excl + v0 + v1 + v2;
  if (t == 255) bsums[blockIdx.x] = s[255];
}

__global__ __launch_bounds__(1024) void scan_sums_kernel(
    int* __restrict__ bsums, int* __restrict__ offsN, int nb) {
  __shared__ int s[1024];
  const int t = threadIdx.x;
  const int v = (t < nb) ? bsums[t] : 0;
  s[t] = v;
  __syncthreads();
  for (int off = 1; off < 1024; off <<= 1) {
    int x = (t >= off) ? s[t - off] : 0;
    __syncthreads();
    s[t] += x;
    __syncthreads();
  }
  if (t < nb) bsums[t] = s[t] - v;   // exclusive chunk offsets
  if (t == nb - 1) *offsN = s[t];    // grand total
}

__global__ __launch_bounds__(256) void scan_add_kernel(
    int* __restrict__ offs, const int* __restrict__ bsums, int N) {
  const int i = blockIdx.x * 256 + threadIdx.x;
  if (i < N) offs[i] += bsums[i >> 10];
}

// generic-path bucket fill (atomic-free via posw ranks)
__global__ __launch_bounds__(256) void bucket_kernel(
    const int* __restrict__ src, const int* __restrict__ dst,
    const float* __restrict__ ew, const int* __restrict__ offs,
    const int* __restrict__ posw, int2* __restrict__ pairs, int E) {
  int e = blockIdx.x * 256 + threadIdx.x;
  if (e < E) {
    const int pos = offs[dst[e]] + posw[e];
    pairs[pos] = make_int2(src[e], __float_as_int(ew[e]));
  }
}

// ---------------------------------------------------------------------------
// Radix CSR build (N <= 65536): NO global atomics. bsums folded into readers
// (scan_add not needed on this path).
// ---------------------------------------------------------------------------
#define NB 256   // level-1 blocks
#define RB 256   // radix bins

__global__ __launch_bounds__(256) void p1_hist_kernel(
    const int* __restrict__ dst, int* __restrict__ countsT, int E, int epb) {
  __shared__ int h[RB];
  const int t = threadIdx.x;
  h[t] = 0;
  __syncthreads();
  const int base = blockIdx.x * epb;
  const int lim = min(base + epb, E);
  for (int i = base + t; i < lim; i += 256) atomicAdd(&h[dst[i] >> 8], 1);
  __syncthreads();
  countsT[t * NB + blockIdx.x] = h[t];
}

__global__ __launch_bounds__(256) void p1_scatter_kernel(
    const int* __restrict__ src, const int* __restrict__ dst,
    const float* __restrict__ ew, const int* __restrict__ SC,
    const int* __restrict__ bsums, int2* __restrict__ tmp, int E, int epb) {
  __shared__ int cur[RB];
  const int t = threadIdx.x;
  const int idx = t * NB + blockIdx.x;
  cur[t] = SC[idx] + bsums[idx >> 10];
  __syncthreads();
  const int base = blockIdx.x * epb;
  const int lim = min(base + epb, E);
  for (int i = base + t; i < lim; i += 256) {
    const int d = dst[i];
    const unsigned s = (unsigned)src[i];
    const float w = ew[i];
    const int pos = atomicAdd(&cur[d >> 8], 1);   // LDS atomic
    tmp[pos] = make_int2((int)((unsigned)d | (s << 16)), __float_as_int(w));
  }
}

__global__ __launch_bounds__(256) void p2_kernel(
    const int2* __restrict__ tmp, const int* __restrict__ SC,
    const int* __restrict__ bsums,
    int* __restrict__ offs, int2* __restrict__ pairs, int N, int E) {
  __shared__ int h[RB];
  __shared__ int s[RB];
  __shared__ int cur[RB];
  const int t = threadIdx.x;
  const int b = blockIdx.x;
  const int segBeg = SC[b * RB] + bsums[b >> 2];
  const int segEnd = (b == RB - 1) ? E : (SC[(b + 1) * RB] + bsums[(b + 1) >> 2]);

  h[t] = 0;
  __syncthreads();
  for (int i = segBeg + t; i < segEnd; i += 256)
    atomicAdd(&h[tmp[i].x & 255], 1);
  __syncthreads();

  const int v = h[t];
  s[t] = v;
  __syncthreads();
  for (int off = 1; off < 256; off <<= 1) {
    int x = (t >= off) ? s[t - off] : 0;
    __syncthreads();
    s[t] += x;
    __syncthreads();
  }
  const int excl = s[t] - v;
  cur[t] = segBeg + excl;
  const int node = b * RB + t;
  if (node <= N) offs[node] = segBeg + excl;  // offs[N] lands here too
  __syncthreads();

  for (int i = segBeg + t; i < segEnd; i += 256) {
    const int2 r = tmp[i];
    const int lo = r.x & 255;
    const int pos = atomicAdd(&cur[lo], 1);    // LDS atomic
    pairs[pos] = make_int2((int)(((unsigned)r.x) >> 16), r.y);
  }
}

// ---------------------------------------------------------------------------
// Gather-aggregate: 16 lanes per node, float4 per lane (one dwordx4 covers
// a row with 16 lanes). 4 nodes per wave, 16 nodes per block. 2-deep unroll
// -> 8 row-fetches in flight per wave.
// ---------------------------------------------------------------------------
template <bool BIAS>
__global__ __launch_bounds__(256) void gather_agg_kernel(
    const float* __restrict__ H, const int* __restrict__ offs,
    const int2* __restrict__ pairs,
    const float* __restrict__ bias, float* __restrict__ out, int N) {
  const int l4 = threadIdx.x & 15;                 // 16B chunk within row
  const int node = blockIdx.x * 16 + (threadIdx.x >> 4);
  if (node >= N) return;
  const int beg = offs[node], end = offs[node + 1];
  float4 A0 = make_float4(0.f, 0.f, 0.f, 0.f);
  float4 A1 = make_float4(0.f, 0.f, 0.f, 0.f);
  int i = beg;
  for (; i + 2 <= end; i += 2) {
    const int2 p0 = pairs[i], p1 = pairs[i + 1];
    const float4 v0 = *reinterpret_cast<const float4*>(H + (size_t)p0.x * D + l4 * 4);
    const float4 v1 = *reinterpret_cast<const float4*>(H + (size_t)p1.x * D + l4 * 4);
    const float w0 = __int_as_float(p0.y), w1 = __int_as_float(p1.y);
    A0.x += w0 * v0.x; A0.y += w0 * v0.y; A0.z += w0 * v0.z; A0.w += w0 * v0.w;
    A1.x += w1 * v1.x; A1.y += w1 * v1.y; A1.z += w1 * v1.z; A1.w += w1 * v1.w;
  }
  if (i < end) {
    const int2 p = pairs[i];
    const float4 v = *reinterpret_cast<const float4*>(H + (size_t)p.x * D + l4 * 4);
    const float w = __int_as_float(p.y);
    A0.x += w * v.x; A0.y += w * v.y; A0.z += w * v.z; A0.w += w * v.w;
  }
  float4 r;
  r.x = A0.x + A1.x; r.y = A0.y + A1.y; r.z = A0.z + A1.z; r.w = A0.w + A1.w;
  if (BIAS) {
    const float4 b = *reinterpret_cast<const float4*>(bias + l4 * 4);
    r.x += b.x; r.y += b.y; r.z += b.z; r.w += b.w;
  }
  *reinterpret_cast<float4*>(out + (size_t)node * D + l4 * 4) = r;
}

// ---------------------- fallback (atomic scatter) path ---------------------
__global__ __launch_bounds__(256) void scatter_kernel(
    const float* __restrict__ H, const float* __restrict__ ew,
    const int* __restrict__ src, const int* __restrict__ dst,
    float* __restrict__ out, int nEdges) {
  const int tid = blockIdx.x * 256 + threadIdx.x;
  const int e = tid >> 4;
  if (e >= nEdges) return;
  const int c = (tid & 15) * 4;
  const float w = ew[e];
  const float4 v = *reinterpret_cast<const float4*>(H + (size_t)src[e] * D + c);
  float* o = out + (size_t)dst[e] * D + c;
  atomicAdd(o + 0, w * v.x);
  atomicAdd(o + 1, w * v.y);
  atomicAdd(o + 2, w * v.z);
  atomicAdd(o + 3, w * v.w);
}

__global__ __launch_bounds__(256) void fill_bias_kernel(
    float* __restrict__ out, const float* __restrict__ b, int total) {
  int i = blockIdx.x * 256 + threadIdx.x;
  if (i < total) out[i] = b[i & 63];
}

// ---------------------------------------------------------------------------
extern "C" void kernel_launch(void* const* d_in, const int* in_sizes, int n_in,
                              void* d_out, int out_size, void* d_ws,
                              size_t ws_size, hipStream_t stream) {
  const float* X  = (const float*)d_in[0];
  const float* ew = (const float*)d_in[1];
  const float* W1 = (const float*)d_in[2];
  const float* b1 = (const float*)d_in[3];
  const float* W2 = (const float*)d_in[4];
  const float* b2 = (const float*)d_in[5];
  const int*   ei = (const int*)d_in[6];

  const int N = in_sizes[0] / D;   // 50000
  const int E = in_sizes[6] / 2;   // 800000
  const int* src = ei;
  const int* dst = ei + E;
  float* out = (float*)d_out;

  // workspace layout
  char* ws = (char*)d_ws;
  float* buf0 = (float*)ws;                 ws += (size_t)N * D * 4;
  float* buf1 = (float*)ws;                 ws += (size_t)N * D * 4;
  const size_t baseBytes = (size_t)(ws - (char*)d_ws);
  int2*  pairs  = (int2*)ws;                ws += (size_t)E * 8;
  int*   offs   = (int*)ws;                 ws += (size_t)(N + 1) * 4;
  const size_t needBytes = (size_t)(ws - (char*)d_ws);

  const int gemmBlocks = (N + 63) / 64;
  const int aggBlocks  = (N + 15) / 16;
  const int edgeBlocks = (E + 255) / 256;

  if (ws_size >= needBytes) {
    if (N <= 65536 && (size_t)N * D * 4 >= (size_t)(2 * NB * RB + 1 + 64) * 4 &&
        (size_t)N * D * 4 >= (size_t)E * 8) {
      // ---- radix build: zero global atomics ----
      int*  countsT = (int*)buf0;                    // 65536
      int*  SC      = (int*)buf0 + NB * RB;          // 65537
      int*  bsums   = (int*)buf0 + 2 * NB * RB + 1;  // 64
      int2* tmp     = (int2*)buf1;                   // E records

      const int epb = (E + NB - 1) / NB;
      p1_hist_kernel<<<NB, 256, 0, stream>>>(dst, countsT, E, epb);
      scan_part_kernel<<<NB * RB / SCAN_CHUNK, 256, 0, stream>>>(countsT, SC, bsums, NB * RB);
      scan_sums_kernel<<<1, 1024, 0, stream>>>(bsums, SC + NB * RB, NB * RB / SCAN_CHUNK);
      p1_scatter_kernel<<<NB, 256, 0, stream>>>(src, dst, ew, SC, bsums, tmp, E, epb);
      p2_kernel<<<RB, 256, 0, stream>>>(tmp, SC, bsums, offs, pairs, N, E);
    } else {
      // ---- generic build: hist(+rank) -> N-scan -> atomic-free bucket ----
      int* deg   = (int*)buf0;
      int* bsums = (int*)buf0 + N;
      int* posw  = (int*)buf1;
      const int nb = (N + SCAN_CHUNK - 1) / SCAN_CHUNK;
      hipMemsetAsync(deg, 0, (size_t)N * 4, stream);
      hist_kernel<<<edgeBlocks, 256, 0, stream>>>(dst, deg, posw, E);
      scan_part_kernel<<<nb, 256, 0, stream>>>(deg, offs, bsums, N);
      scan_sums_kernel<<<1, 1024, 0, stream>>>(bsums, offs + N, nb);
      scan_add_kernel<<<(N + 255) / 256, 256, 0, stream>>>(offs, bsums, N);
      bucket_kernel<<<edgeBlocks, 256, 0, stream>>>(src, dst, ew, offs, posw, pairs, E);
    }

    // ---- pipeline ----
    gemm64_kernel<false><<<gemmBlocks, 256, 0, stream>>>(X, W1, nullptr, buf0, N);
    gather_agg_kernel<false><<<aggBlocks, 256, 0, stream>>>(buf0, offs, pairs, nullptr, buf1, N);
    gemm64_kernel<true><<<gemmBlocks, 256, 0, stream>>>(buf1, W2, b1, buf0, N);
    gather_agg_kernel<true><<<aggBlocks, 256, 0, stream>>>(buf0, offs, pairs, b2, out, N);
  } else if (ws_size >= baseBytes) {
    // ---- fallback: atomic scatter (slow but correct) ----
    const int scatBlocks = (E * 16 + 255) / 256;
    const int fillBlocks = (N * D + 255) / 256;
    gemm64_kernel<false><<<gemmBlocks, 256, 0, stream>>>(X, W1, nullptr, buf0, N);
    hipMemsetAsync(buf1, 0, (size_t)N * D * 4, stream);
    scatter_kernel<<<scatBlocks, 256, 0, stream>>>(buf0, ew, src, dst, buf1, E);
    gemm64_kernel<true><<<gemmBlocks, 256, 0, stream>>>(buf1, W2, b1, buf0, N);
    fill_bias_kernel<<<fillBlocks, 256, 0, stream>>>(out, b2, N * D);
    scatter_kernel<<<scatBlocks, 256, 0, stream>>>(buf0, ew, src, dst, out, E);
  }
}

// Round 7
// 117.166 us; speedup vs baseline: 2.7493x; 1.0590x over previous
//
#include <hip/hip_runtime.h>

#define D 64  // feature dim for all layers

// ---------------------------------------------------------------------------
// GEMM: out = f(A) @ W, A is N x 64, W is 64 x 64.
//   PRE=false: f(x) = x ; PRE=true: f(x) = relu(x + bpre[k]) (input-side fuse)
// 64x64 tile per block, 256 threads, 4x4 outputs/thread, LDS pad 68.
// __launch_bounds__(256,4): cap VGPR so 4 blocks/CU stay resident
// (R5 post-mortem: 256 VGPR -> 9% occupancy -> latency-bound, 55us).
// ---------------------------------------------------------------------------
template <bool PRE>
__global__ __launch_bounds__(256, 4) void gemm64_kernel(
    const float* __restrict__ A, const float* __restrict__ W,
    const float* __restrict__ bpre, float* __restrict__ out, int N) {
  __shared__ float sA[64][68];
  __shared__ float sW[64][68];
  const int t = threadIdx.x;
  const int rowBase = blockIdx.x * 64;

#pragma unroll
  for (int i = t * 4; i < 4096; i += 1024) {
    const int k = i >> 6, c = i & 63;
    *reinterpret_cast<float4*>(&sW[k][c]) =
        *reinterpret_cast<const float4*>(W + i);
  }
#pragma unroll
  for (int i = t * 4; i < 4096; i += 1024) {
    const int r = i >> 6, k = i & 63;
    const int row = rowBase + r;
    float4 a = make_float4(0.f, 0.f, 0.f, 0.f);
    if (row < N) a = *reinterpret_cast<const float4*>(A + (size_t)row * D + k);
    if (PRE) {
      const float4 b = *reinterpret_cast<const float4*>(bpre + k);
      a.x = fmaxf(a.x + b.x, 0.f);
      a.y = fmaxf(a.y + b.y, 0.f);
      a.z = fmaxf(a.z + b.z, 0.f);
      a.w = fmaxf(a.w + b.w, 0.f);
    }
    *reinterpret_cast<float4*>(&sA[r][k]) = a;
  }
  __syncthreads();

  const int ty = t >> 4, tx = t & 15;
  float4 acc0 = make_float4(0.f, 0.f, 0.f, 0.f);
  float4 acc1 = make_float4(0.f, 0.f, 0.f, 0.f);
  float4 acc2 = make_float4(0.f, 0.f, 0.f, 0.f);
  float4 acc3 = make_float4(0.f, 0.f, 0.f, 0.f);

#pragma unroll 4
  for (int kq = 0; kq < 16; ++kq) {
    const float4 w0 = *reinterpret_cast<const float4*>(&sW[kq * 4 + 0][tx * 4]);
    const float4 w1 = *reinterpret_cast<const float4*>(&sW[kq * 4 + 1][tx * 4]);
    const float4 w2 = *reinterpret_cast<const float4*>(&sW[kq * 4 + 2][tx * 4]);
    const float4 w3 = *reinterpret_cast<const float4*>(&sW[kq * 4 + 3][tx * 4]);
    const float4 a0 = *reinterpret_cast<const float4*>(&sA[ty * 4 + 0][kq * 4]);
    const float4 a1 = *reinterpret_cast<const float4*>(&sA[ty * 4 + 1][kq * 4]);
    const float4 a2 = *reinterpret_cast<const float4*>(&sA[ty * 4 + 2][kq * 4]);
    const float4 a3 = *reinterpret_cast<const float4*>(&sA[ty * 4 + 3][kq * 4]);
#define FMA4(ACC, AV)                                                     \
    ACC.x += AV.x * w0.x + AV.y * w1.x + AV.z * w2.x + AV.w * w3.x;       \
    ACC.y += AV.x * w0.y + AV.y * w1.y + AV.z * w2.y + AV.w * w3.y;       \
    ACC.z += AV.x * w0.z + AV.y * w1.z + AV.z * w2.z + AV.w * w3.z;       \
    ACC.w += AV.x * w0.w + AV.y * w1.w + AV.z * w2.w + AV.w * w3.w;
    FMA4(acc0, a0) FMA4(acc1, a1) FMA4(acc2, a2) FMA4(acc3, a3)
#undef FMA4
  }

  const int row0 = rowBase + ty * 4;
  if (row0 + 0 < N) *reinterpret_cast<float4*>(out + (size_t)(row0 + 0) * D + tx * 4) = acc0;
  if (row0 + 1 < N) *reinterpret_cast<float4*>(out + (size_t)(row0 + 1) * D + tx * 4) = acc1;
  if (row0 + 2 < N) *reinterpret_cast<float4*>(out + (size_t)(row0 + 2) * D + tx * 4) = acc2;
  if (row0 + 3 < N) *reinterpret_cast<float4*>(out + (size_t)(row0 + 3) * D + tx * 4) = acc3;
}

// ---------------------------------------------------------------------------
// FUSED: out[row] = relu(agg(H)[row] + b1) @ W  (gather + gemm2 in one pass).
// Gather output row n is consumed only by gemm row n -> fuse per 64-node
// tile; saves the 12.8MB intermediate write + re-read and one launch.
// Phase A: 4 passes x 16 nodes (16 lanes/node, float4/lane, 4-deep MLP).
// Phase B: the gemm64 inner loop on LDS.
// ---------------------------------------------------------------------------
__global__ __launch_bounds__(256, 4) void agg_gemm_kernel(
    const float* __restrict__ H, const int* __restrict__ offs,
    const int2* __restrict__ pairs, const float* __restrict__ b1,
    const float* __restrict__ W, float* __restrict__ out, int N) {
  __shared__ float sA[64][68];
  __shared__ float sW[64][68];
  const int t = threadIdx.x;
  const int rowBase = blockIdx.x * 64;

#pragma unroll
  for (int i = t * 4; i < 4096; i += 1024) {
    const int k = i >> 6, c = i & 63;
    *reinterpret_cast<float4*>(&sW[k][c]) =
        *reinterpret_cast<const float4*>(W + i);
  }

  const int l4 = t & 15;
  const int sub = t >> 4;
  const float4 bb = *reinterpret_cast<const float4*>(b1 + l4 * 4);
#pragma unroll
  for (int p = 0; p < 4; ++p) {
    const int r = p * 16 + sub;
    const int node = rowBase + r;
    float4 A0 = make_float4(0.f, 0.f, 0.f, 0.f);
    float4 A1 = make_float4(0.f, 0.f, 0.f, 0.f);
    float4 A2 = make_float4(0.f, 0.f, 0.f, 0.f);
    float4 A3 = make_float4(0.f, 0.f, 0.f, 0.f);
    if (node < N) {
      const int beg = offs[node], end = offs[node + 1];
      int i = beg;
      for (; i + 4 <= end; i += 4) {
        const int2 p0 = pairs[i], p1 = pairs[i + 1], p2 = pairs[i + 2], p3 = pairs[i + 3];
        const float4 v0 = *reinterpret_cast<const float4*>(H + (size_t)p0.x * D + l4 * 4);
        const float4 v1 = *reinterpret_cast<const float4*>(H + (size_t)p1.x * D + l4 * 4);
        const float4 v2 = *reinterpret_cast<const float4*>(H + (size_t)p2.x * D + l4 * 4);
        const float4 v3 = *reinterpret_cast<const float4*>(H + (size_t)p3.x * D + l4 * 4);
        const float w0 = __int_as_float(p0.y), w1 = __int_as_float(p1.y);
        const float w2 = __int_as_float(p2.y), w3 = __int_as_float(p3.y);
        A0.x += w0 * v0.x; A0.y += w0 * v0.y; A0.z += w0 * v0.z; A0.w += w0 * v0.w;
        A1.x += w1 * v1.x; A1.y += w1 * v1.y; A1.z += w1 * v1.z; A1.w += w1 * v1.w;
        A2.x += w2 * v2.x; A2.y += w2 * v2.y; A2.z += w2 * v2.z; A2.w += w2 * v2.w;
        A3.x += w3 * v3.x; A3.y += w3 * v3.y; A3.z += w3 * v3.z; A3.w += w3 * v3.w;
      }
      for (; i < end; ++i) {
        const int2 pp = pairs[i];
        const float4 v = *reinterpret_cast<const float4*>(H + (size_t)pp.x * D + l4 * 4);
        const float w = __int_as_float(pp.y);
        A0.x += w * v.x; A0.y += w * v.y; A0.z += w * v.z; A0.w += w * v.w;
      }
    }
    float4 rr;
    rr.x = fmaxf((A0.x + A1.x) + (A2.x + A3.x) + bb.x, 0.f);
    rr.y = fmaxf((A0.y + A1.y) + (A2.y + A3.y) + bb.y, 0.f);
    rr.z = fmaxf((A0.z + A1.z) + (A2.z + A3.z) + bb.z, 0.f);
    rr.w = fmaxf((A0.w + A1.w) + (A2.w + A3.w) + bb.w, 0.f);
    *reinterpret_cast<float4*>(&sA[r][l4 * 4]) = rr;
  }
  __syncthreads();

  const int ty = t >> 4, tx = t & 15;
  float4 acc0 = make_float4(0.f, 0.f, 0.f, 0.f);
  float4 acc1 = make_float4(0.f, 0.f, 0.f, 0.f);
  float4 acc2 = make_float4(0.f, 0.f, 0.f, 0.f);
  float4 acc3 = make_float4(0.f, 0.f, 0.f, 0.f);

#pragma unroll 4
  for (int kq = 0; kq < 16; ++kq) {
    const float4 w0 = *reinterpret_cast<const float4*>(&sW[kq * 4 + 0][tx * 4]);
    const float4 w1 = *reinterpret_cast<const float4*>(&sW[kq * 4 + 1][tx * 4]);
    const float4 w2 = *reinterpret_cast<const float4*>(&sW[kq * 4 + 2][tx * 4]);
    const float4 w3 = *reinterpret_cast<const float4*>(&sW[kq * 4 + 3][tx * 4]);
    const float4 a0 = *reinterpret_cast<const float4*>(&sA[ty * 4 + 0][kq * 4]);
    const float4 a1 = *reinterpret_cast<const float4*>(&sA[ty * 4 + 1][kq * 4]);
    const float4 a2 = *reinterpret_cast<const float4*>(&sA[ty * 4 + 2][kq * 4]);
    const float4 a3 = *reinterpret_cast<const float4*>(&sA[ty * 4 + 3][kq * 4]);
#define FMA4(ACC, AV)                                                     \
    ACC.x += AV.x * w0.x + AV.y * w1.x + AV.z * w2.x + AV.w * w3.x;       \
    ACC.y += AV.x * w0.y + AV.y * w1.y + AV.z * w2.y + AV.w * w3.y;       \
    ACC.z += AV.x * w0.z + AV.y * w1.z + AV.z * w2.z + AV.w * w3.z;       \
    ACC.w += AV.x * w0.w + AV.y * w1.w + AV.z * w2.w + AV.w * w3.w;
    FMA4(acc0, a0) FMA4(acc1, a1) FMA4(acc2, a2) FMA4(acc3, a3)
#undef FMA4
  }

  const int row0 = rowBase + ty * 4;
  if (row0 + 0 < N) *reinterpret_cast<float4*>(out + (size_t)(row0 + 0) * D + tx * 4) = acc0;
  if (row0 + 1 < N) *reinterpret_cast<float4*>(out + (size_t)(row0 + 1) * D + tx * 4) = acc1;
  if (row0 + 2 < N) *reinterpret_cast<float4*>(out + (size_t)(row0 + 2) * D + tx * 4) = acc2;
  if (row0 + 3 < N) *reinterpret_cast<float4*>(out + (size_t)(row0 + 3) * D + tx * 4) = acc3;
}

// ---------------------------------------------------------------------------
// Generic CSR build (N > 65536 path): hist(+rank) atomics
// ---------------------------------------------------------------------------
__global__ __launch_bounds__(256) void hist_kernel(
    const int* __restrict__ dst, int* __restrict__ deg,
    int* __restrict__ posw, int E) {
  int e = blockIdx.x * 256 + threadIdx.x;
  if (e < E) posw[e] = atomicAdd(&deg[dst[e]], 1);
}

// ---- device-wide exclusive scan, 3 kernels -------------------------------
#define SCAN_CHUNK 1024
__global__ __launch_bounds__(256) void scan_part_kernel(
    const int* __restrict__ deg, int* __restrict__ offs,
    int* __restrict__ bsums, int N) {
  __shared__ int s[256];
  const int t = threadIdx.x;
  const int base = blockIdx.x * SCAN_CHUNK + t * 4;
  int v0 = 0, v1 = 0, v2 = 0, v3 = 0;
  if (base + 3 < N) {
    const int4 v = *reinterpret_cast<const int4*>(deg + base);
    v0 = v.x; v1 = v.y; v2 = v.z; v3 = v.w;
  } else {
    if (base + 0 < N) v0 = deg[base + 0];
    if (base + 1 < N) v1 = deg[base + 1];
    if (base + 2 < N) v2 = deg[base + 2];
  }
  const int tsum = v0 + v1 + v2 + v3;
  s[t] = tsum;
  __syncthreads();
  for (int off = 1; off < 256; off <<= 1) {
    int x = (t >= off) ? s[t - off] : 0;
    __syncthreads();
    s[t] += x;
    __syncthreads();
  }
  const int excl = s[t] - tsum;
  if (base + 0 < N) offs[base + 0] = excl;
  if (base + 1 < N) offs[base + 1] = excl + v0;
  if (base + 2 < N) offs[base + 2] = excl + v0 + v1;
  if (base + 3 < N) offs[base + 3] = excl + v0 + v1 + v2;
  if (t == 255) bsums[blockIdx.x] = s[255];
}

__global__ __launch_bounds__(1024) void scan_sums_kernel(
    int* __restrict__ bsums, int* __restrict__ offsN, int nb) {
  __shared__ int s[1024];
  const int t = threadIdx.x;
  const int v = (t < nb) ? bsums[t] : 0;
  s[t] = v;
  __syncthreads();
  for (int off = 1; off < 1024; off <<= 1) {
    int x = (t >= off) ? s[t - off] : 0;
    __syncthreads();
    s[t] += x;
    __syncthreads();
  }
  if (t < nb) bsums[t] = s[t] - v;   // exclusive chunk offsets
  if (t == nb - 1) *offsN = s[t];    // grand total
}

__global__ __launch_bounds__(256) void scan_add_kernel(
    int* __restrict__ offs, const int* __restrict__ bsums, int N) {
  const int i = blockIdx.x * 256 + threadIdx.x;
  if (i < N) offs[i] += bsums[i >> 10];
}

// generic-path bucket fill (atomic-free via posw ranks)
__global__ __launch_bounds__(256) void bucket_kernel(
    const int* __restrict__ src, const int* __restrict__ dst,
    const float* __restrict__ ew, const int* __restrict__ offs,
    const int* __restrict__ posw, int2* __restrict__ pairs, int E) {
  int e = blockIdx.x * 256 + threadIdx.x;
  if (e < E) {
    const int pos = offs[dst[e]] + posw[e];
    pairs[pos] = make_int2(src[e], __float_as_int(ew[e]));
  }
}

// ---------------------------------------------------------------------------
// Radix CSR build (N <= 65536): NO global atomics.
// ---------------------------------------------------------------------------
#define NB 256   // level-1 blocks
#define RB 256   // radix bins

__global__ __launch_bounds__(256) void p1_hist_kernel(
    const int* __restrict__ dst, int* __restrict__ countsT, int E, int epb) {
  __shared__ int h[RB];
  const int t = threadIdx.x;
  h[t] = 0;
  __syncthreads();
  const int base = blockIdx.x * epb;
  const int lim = min(base + epb, E);
  for (int i = base + t; i < lim; i += 256) atomicAdd(&h[dst[i] >> 8], 1);
  __syncthreads();
  countsT[t * NB + blockIdx.x] = h[t];
}

__global__ __launch_bounds__(256) void p1_scatter_kernel(
    const int* __restrict__ src, const int* __restrict__ dst,
    const float* __restrict__ ew, const int* __restrict__ SC,
    const int* __restrict__ bsums, int2* __restrict__ tmp, int E, int epb) {
  __shared__ int cur[RB];
  const int t = threadIdx.x;
  const int idx = t * NB + blockIdx.x;
  cur[t] = SC[idx] + bsums[idx >> 10];
  __syncthreads();
  const int base = blockIdx.x * epb;
  const int lim = min(base + epb, E);
  for (int i = base + t; i < lim; i += 256) {
    const int d = dst[i];
    const unsigned s = (unsigned)src[i];
    const float w = ew[i];
    const int pos = atomicAdd(&cur[d >> 8], 1);   // LDS atomic
    tmp[pos] = make_int2((int)((unsigned)d | (s << 16)), __float_as_int(w));
  }
}

__global__ __launch_bounds__(256) void p2_kernel(
    const int2* __restrict__ tmp, const int* __restrict__ SC,
    const int* __restrict__ bsums,
    int* __restrict__ offs, int2* __restrict__ pairs, int N, int E) {
  __shared__ int h[RB];
  __shared__ int s[RB];
  __shared__ int cur[RB];
  const int t = threadIdx.x;
  const int b = blockIdx.x;
  const int segBeg = SC[b * RB] + bsums[b >> 2];
  const int segEnd = (b == RB - 1) ? E : (SC[(b + 1) * RB] + bsums[(b + 1) >> 2]);

  h[t] = 0;
  __syncthreads();
  for (int i = segBeg + t; i < segEnd; i += 256)
    atomicAdd(&h[tmp[i].x & 255], 1);
  __syncthreads();

  const int v = h[t];
  s[t] = v;
  __syncthreads();
  for (int off = 1; off < 256; off <<= 1) {
    int x = (t >= off) ? s[t - off] : 0;
    __syncthreads();
    s[t] += x;
    __syncthreads();
  }
  const int excl = s[t] - v;
  cur[t] = segBeg + excl;
  const int node = b * RB + t;
  if (node <= N) offs[node] = segBeg + excl;
  __syncthreads();

  for (int i = segBeg + t; i < segEnd; i += 256) {
    const int2 r = tmp[i];
    const int lo = r.x & 255;
    const int pos = atomicAdd(&cur[lo], 1);    // LDS atomic
    pairs[pos] = make_int2((int)(((unsigned)r.x) >> 16), r.y);
  }
}

// ---------------------------------------------------------------------------
// Gather-aggregate (final layer): 16 lanes/node, float4/lane, 4-deep MLP.
// ---------------------------------------------------------------------------
template <bool BIAS>
__global__ __launch_bounds__(256) void gather_agg_kernel(
    const float* __restrict__ H, const int* __restrict__ offs,
    const int2* __restrict__ pairs,
    const float* __restrict__ bias, float* __restrict__ out, int N) {
  const int l4 = threadIdx.x & 15;
  const int node = blockIdx.x * 16 + (threadIdx.x >> 4);
  if (node >= N) return;
  const int beg = offs[node], end = offs[node + 1];
  float4 A0 = make_float4(0.f, 0.f, 0.f, 0.f);
  float4 A1 = make_float4(0.f, 0.f, 0.f, 0.f);
  float4 A2 = make_float4(0.f, 0.f, 0.f, 0.f);
  float4 A3 = make_float4(0.f, 0.f, 0.f, 0.f);
  int i = beg;
  for (; i + 4 <= end; i += 4) {
    const int2 p0 = pairs[i], p1 = pairs[i + 1], p2 = pairs[i + 2], p3 = pairs[i + 3];
    const float4 v0 = *reinterpret_cast<const float4*>(H + (size_t)p0.x * D + l4 * 4);
    const float4 v1 = *reinterpret_cast<const float4*>(H + (size_t)p1.x * D + l4 * 4);
    const float4 v2 = *reinterpret_cast<const float4*>(H + (size_t)p2.x * D + l4 * 4);
    const float4 v3 = *reinterpret_cast<const float4*>(H + (size_t)p3.x * D + l4 * 4);
    const float w0 = __int_as_float(p0.y), w1 = __int_as_float(p1.y);
    const float w2 = __int_as_float(p2.y), w3 = __int_as_float(p3.y);
    A0.x += w0 * v0.x; A0.y += w0 * v0.y; A0.z += w0 * v0.z; A0.w += w0 * v0.w;
    A1.x += w1 * v1.x; A1.y += w1 * v1.y; A1.z += w1 * v1.z; A1.w += w1 * v1.w;
    A2.x += w2 * v2.x; A2.y += w2 * v2.y; A2.z += w2 * v2.z; A2.w += w2 * v2.w;
    A3.x += w3 * v3.x; A3.y += w3 * v3.y; A3.z += w3 * v3.z; A3.w += w3 * v3.w;
  }
  for (; i < end; ++i) {
    const int2 p = pairs[i];
    const float4 v = *reinterpret_cast<const float4*>(H + (size_t)p.x * D + l4 * 4);
    const float w = __int_as_float(p.y);
    A0.x += w * v.x; A0.y += w * v.y; A0.z += w * v.z; A0.w += w * v.w;
  }
  float4 r;
  r.x = (A0.x + A1.x) + (A2.x + A3.x);
  r.y = (A0.y + A1.y) + (A2.y + A3.y);
  r.z = (A0.z + A1.z) + (A2.z + A3.z);
  r.w = (A0.w + A1.w) + (A2.w + A3.w);
  if (BIAS) {
    const float4 b = *reinterpret_cast<const float4*>(bias + l4 * 4);
    r.x += b.x; r.y += b.y; r.z += b.z; r.w += b.w;
  }
  *reinterpret_cast<float4*>(out + (size_t)node * D + l4 * 4) = r;
}

// ---------------------- fallback (atomic scatter) path ---------------------
__global__ __launch_bounds__(256) void scatter_kernel(
    const float* __restrict__ H, const float* __restrict__ ew,
    const int* __restrict__ src, const int* __restrict__ dst,
    float* __restrict__ out, int nEdges) {
  const int tid = blockIdx.x * 256 + threadIdx.x;
  const int e = tid >> 4;
  if (e >= nEdges) return;
  const int c = (tid & 15) * 4;
  const float w = ew[e];
  const float4 v = *reinterpret_cast<const float4*>(H + (size_t)src[e] * D + c);
  float* o = out + (size_t)dst[e] * D + c;
  atomicAdd(o + 0, w * v.x);
  atomicAdd(o + 1, w * v.y);
  atomicAdd(o + 2, w * v.z);
  atomicAdd(o + 3, w * v.w);
}

__global__ __launch_bounds__(256) void fill_bias_kernel(
    float* __restrict__ out, const float* __restrict__ b, int total) {
  int i = blockIdx.x * 256 + threadIdx.x;
  if (i < total) out[i] = b[i & 63];
}

// ---------------------------------------------------------------------------
extern "C" void kernel_launch(void* const* d_in, const int* in_sizes, int n_in,
                              void* d_out, int out_size, void* d_ws,
                              size_t ws_size, hipStream_t stream) {
  const float* X  = (const float*)d_in[0];
  const float* ew = (const float*)d_in[1];
  const float* W1 = (const float*)d_in[2];
  const float* b1 = (const float*)d_in[3];
  const float* W2 = (const float*)d_in[4];
  const float* b2 = (const float*)d_in[5];
  const int*   ei = (const int*)d_in[6];

  const int N = in_sizes[0] / D;   // 50000
  const int E = in_sizes[6] / 2;   // 800000
  const int* src = ei;
  const int* dst = ei + E;
  float* out = (float*)d_out;

  // workspace layout
  char* ws = (char*)d_ws;
  float* buf0 = (float*)ws;                 ws += (size_t)N * D * 4;
  float* buf1 = (float*)ws;                 ws += (size_t)N * D * 4;
  const size_t baseBytes = (size_t)(ws - (char*)d_ws);
  int2*  pairs  = (int2*)ws;                ws += (size_t)E * 8;
  int*   offs   = (int*)ws;                 ws += (size_t)(N + 1) * 4;
  const size_t needBytes = (size_t)(ws - (char*)d_ws);

  const int gemmBlocks = (N + 63) / 64;
  const int aggBlocks  = (N + 15) / 16;
  const int edgeBlocks = (E + 255) / 256;

  if (ws_size >= needBytes) {
    if (N <= 65536 && (size_t)N * D * 4 >= (size_t)(2 * NB * RB + 1 + 64) * 4 &&
        (size_t)N * D * 4 >= (size_t)E * 8) {
      // ---- radix build: zero global atomics ----
      int*  countsT = (int*)buf0;                    // 65536
      int*  SC      = (int*)buf0 + NB * RB;          // 65537
      int*  bsums   = (int*)buf0 + 2 * NB * RB + 1;  // 64
      int2* tmp     = (int2*)buf1;                   // E records

      const int epb = (E + NB - 1) / NB;
      p1_hist_kernel<<<NB, 256, 0, stream>>>(dst, countsT, E, epb);
      scan_part_kernel<<<NB * RB / SCAN_CHUNK, 256, 0, stream>>>(countsT, SC, bsums, NB * RB);
      scan_sums_kernel<<<1, 1024, 0, stream>>>(bsums, SC + NB * RB, NB * RB / SCAN_CHUNK);
      p1_scatter_kernel<<<NB, 256, 0, stream>>>(src, dst, ew, SC, bsums, tmp, E, epb);
      p2_kernel<<<RB, 256, 0, stream>>>(tmp, SC, bsums, offs, pairs, N, E);
    } else {
      // ---- generic build: hist(+rank) -> N-scan -> atomic-free bucket ----
      int* deg   = (int*)buf0;
      int* bsums = (int*)buf0 + N;
      int* posw  = (int*)buf1;
      const int nb = (N + SCAN_CHUNK - 1) / SCAN_CHUNK;
      hipMemsetAsync(deg, 0, (size_t)N * 4, stream);
      hist_kernel<<<edgeBlocks, 256, 0, stream>>>(dst, deg, posw, E);
      scan_part_kernel<<<nb, 256, 0, stream>>>(deg, offs, bsums, N);
      scan_sums_kernel<<<1, 1024, 0, stream>>>(bsums, offs + N, nb);
      scan_add_kernel<<<(N + 255) / 256, 256, 0, stream>>>(offs, bsums, N);
      bucket_kernel<<<edgeBlocks, 256, 0, stream>>>(src, dst, ew, offs, posw, pairs, E);
    }

    // ---- pipeline: gemm1 -> fused(agg+relu+gemm2) -> final agg ----
    gemm64_kernel<false><<<gemmBlocks, 256, 0, stream>>>(X, W1, nullptr, buf0, N);
    agg_gemm_kernel<<<gemmBlocks, 256, 0, stream>>>(buf0, offs, pairs, b1, W2, buf1, N);
    gather_agg_kernel<true><<<aggBlocks, 256, 0, stream>>>(buf1, offs, pairs, b2, out, N);
  } else if (ws_size >= baseBytes) {
    // ---- fallback: atomic scatter (slow but correct) ----
    const int scatBlocks = (E * 16 + 255) / 256;
    const int fillBlocks = (N * D + 255) / 256;
    gemm64_kernel<false><<<gemmBlocks, 256, 0, stream>>>(X, W1, nullptr, buf0, N);
    hipMemsetAsync(buf1, 0, (size_t)N * D * 4, stream);
    scatter_kernel<<<scatBlocks, 256, 0, stream>>>(buf0, ew, src, dst, buf1, E);
    gemm64_kernel<true><<<gemmBlocks, 256, 0, stream>>>(buf1, W2, b1, buf0, N);
    fill_bias_kernel<<<fillBlocks, 256, 0, stream>>>(out, b2, N * D);
    scatter_kernel<<<scatBlocks, 256, 0, stream>>>(buf0, ew, src, dst, out, E);
  }
}

// Round 8
// 116.294 us; speedup vs baseline: 2.7699x; 1.0075x over previous
//
#include <hip/hip_runtime.h>

#define D 64  // feature dim for all layers

#define NB 256   // level-1 edge-partition blocks
#define RB 256   // radix bins (dst>>8)

// ---------------------------------------------------------------------------
// GEMM: out = f(A) @ W, A is N x 64, W is 64 x 64.  (fallback/generic paths)
//   PRE=false: f(x) = x ; PRE=true: f(x) = relu(x + bpre[k])
// 64x64 tile, 256 threads, 4x4 outputs/thread, LDS pad 68.
// __launch_bounds__(256,4): cap VGPR so 4 blocks/CU stay resident.
// ---------------------------------------------------------------------------
template <bool PRE>
__global__ __launch_bounds__(256, 4) void gemm64_kernel(
    const float* __restrict__ A, const float* __restrict__ W,
    const float* __restrict__ bpre, float* __restrict__ out, int N) {
  __shared__ float sA[64][68];
  __shared__ float sW[64][68];
  const int t = threadIdx.x;
  const int rowBase = blockIdx.x * 64;

#pragma unroll
  for (int i = t * 4; i < 4096; i += 1024) {
    const int k = i >> 6, c = i & 63;
    *reinterpret_cast<float4*>(&sW[k][c]) =
        *reinterpret_cast<const float4*>(W + i);
  }
#pragma unroll
  for (int i = t * 4; i < 4096; i += 1024) {
    const int r = i >> 6, k = i & 63;
    const int row = rowBase + r;
    float4 a = make_float4(0.f, 0.f, 0.f, 0.f);
    if (row < N) a = *reinterpret_cast<const float4*>(A + (size_t)row * D + k);
    if (PRE) {
      const float4 b = *reinterpret_cast<const float4*>(bpre + k);
      a.x = fmaxf(a.x + b.x, 0.f);
      a.y = fmaxf(a.y + b.y, 0.f);
      a.z = fmaxf(a.z + b.z, 0.f);
      a.w = fmaxf(a.w + b.w, 0.f);
    }
    *reinterpret_cast<float4*>(&sA[r][k]) = a;
  }
  __syncthreads();

  const int ty = t >> 4, tx = t & 15;
  float4 acc0 = make_float4(0.f, 0.f, 0.f, 0.f);
  float4 acc1 = make_float4(0.f, 0.f, 0.f, 0.f);
  float4 acc2 = make_float4(0.f, 0.f, 0.f, 0.f);
  float4 acc3 = make_float4(0.f, 0.f, 0.f, 0.f);

#pragma unroll 4
  for (int kq = 0; kq < 16; ++kq) {
    const float4 w0 = *reinterpret_cast<const float4*>(&sW[kq * 4 + 0][tx * 4]);
    const float4 w1 = *reinterpret_cast<const float4*>(&sW[kq * 4 + 1][tx * 4]);
    const float4 w2 = *reinterpret_cast<const float4*>(&sW[kq * 4 + 2][tx * 4]);
    const float4 w3 = *reinterpret_cast<const float4*>(&sW[kq * 4 + 3][tx * 4]);
    const float4 a0 = *reinterpret_cast<const float4*>(&sA[ty * 4 + 0][kq * 4]);
    const float4 a1 = *reinterpret_cast<const float4*>(&sA[ty * 4 + 1][kq * 4]);
    const float4 a2 = *reinterpret_cast<const float4*>(&sA[ty * 4 + 2][kq * 4]);
    const float4 a3 = *reinterpret_cast<const float4*>(&sA[ty * 4 + 3][kq * 4]);
#define FMA4(ACC, AV)                                                     \
    ACC.x += AV.x * w0.x + AV.y * w1.x + AV.z * w2.x + AV.w * w3.x;       \
    ACC.y += AV.x * w0.y + AV.y * w1.y + AV.z * w2.y + AV.w * w3.y;       \
    ACC.z += AV.x * w0.z + AV.y * w1.z + AV.z * w2.z + AV.w * w3.z;       \
    ACC.w += AV.x * w0.w + AV.y * w1.w + AV.z * w2.w + AV.w * w3.w;
    FMA4(acc0, a0) FMA4(acc1, a1) FMA4(acc2, a2) FMA4(acc3, a3)
#undef FMA4
  }

  const int row0 = rowBase + ty * 4;
  if (row0 + 0 < N) *reinterpret_cast<float4*>(out + (size_t)(row0 + 0) * D + tx * 4) = acc0;
  if (row0 + 1 < N) *reinterpret_cast<float4*>(out + (size_t)(row0 + 1) * D + tx * 4) = acc1;
  if (row0 + 2 < N) *reinterpret_cast<float4*>(out + (size_t)(row0 + 2) * D + tx * 4) = acc2;
  if (row0 + 3 < N) *reinterpret_cast<float4*>(out + (size_t)(row0 + 3) * D + tx * 4) = acc3;
}

// ---------------------------------------------------------------------------
// MERGED kernel 1 (radix path): blocks [0, NB) do the coarse histogram
// (block-major countsB[blk*RB+bin], no zeroing pass needed); blocks [NB, ..)
// do gemm1 = X @ W1. Independent work; one launch, hist hides under gemm.
// ---------------------------------------------------------------------------
__global__ __launch_bounds__(256, 4) void hist_gemm_kernel(
    const int* __restrict__ dst, int* __restrict__ countsB, int E, int epb,
    const float* __restrict__ A, const float* __restrict__ W,
    float* __restrict__ out, int N) {
  __shared__ float sA[64][68];
  __shared__ float sW[64][68];
  const int t = threadIdx.x;

  if ((int)blockIdx.x < NB) {
    // ---- histogram part ----
    int* h = reinterpret_cast<int*>(&sA[0][0]);
    h[t] = 0;
    __syncthreads();
    const int base = blockIdx.x * epb;
    const int lim = min(base + epb, E);
    for (int i = base + t; i < lim; i += 256) atomicAdd(&h[dst[i] >> 8], 1);
    __syncthreads();
    countsB[blockIdx.x * RB + t] = h[t];   // coalesced, block-major
    return;
  }

  // ---- gemm part ----
  const int rowBase = ((int)blockIdx.x - NB) * 64;
#pragma unroll
  for (int i = t * 4; i < 4096; i += 1024) {
    const int k = i >> 6, c = i & 63;
    *reinterpret_cast<float4*>(&sW[k][c]) =
        *reinterpret_cast<const float4*>(W + i);
  }
#pragma unroll
  for (int i = t * 4; i < 4096; i += 1024) {
    const int r = i >> 6, k = i & 63;
    const int row = rowBase + r;
    float4 a = make_float4(0.f, 0.f, 0.f, 0.f);
    if (row < N) a = *reinterpret_cast<const float4*>(A + (size_t)row * D + k);
    *reinterpret_cast<float4*>(&sA[r][k]) = a;
  }
  __syncthreads();

  const int ty = t >> 4, tx = t & 15;
  float4 acc0 = make_float4(0.f, 0.f, 0.f, 0.f);
  float4 acc1 = make_float4(0.f, 0.f, 0.f, 0.f);
  float4 acc2 = make_float4(0.f, 0.f, 0.f, 0.f);
  float4 acc3 = make_float4(0.f, 0.f, 0.f, 0.f);

#pragma unroll 4
  for (int kq = 0; kq < 16; ++kq) {
    const float4 w0 = *reinterpret_cast<const float4*>(&sW[kq * 4 + 0][tx * 4]);
    const float4 w1 = *reinterpret_cast<const float4*>(&sW[kq * 4 + 1][tx * 4]);
    const float4 w2 = *reinterpret_cast<const float4*>(&sW[kq * 4 + 2][tx * 4]);
    const float4 w3 = *reinterpret_cast<const float4*>(&sW[kq * 4 + 3][tx * 4]);
    const float4 a0 = *reinterpret_cast<const float4*>(&sA[ty * 4 + 0][kq * 4]);
    const float4 a1 = *reinterpret_cast<const float4*>(&sA[ty * 4 + 1][kq * 4]);
    const float4 a2 = *reinterpret_cast<const float4*>(&sA[ty * 4 + 2][kq * 4]);
    const float4 a3 = *reinterpret_cast<const float4*>(&sA[ty * 4 + 3][kq * 4]);
#define FMA4(ACC, AV)                                                     \
    ACC.x += AV.x * w0.x + AV.y * w1.x + AV.z * w2.x + AV.w * w3.x;       \
    ACC.y += AV.x * w0.y + AV.y * w1.y + AV.z * w2.y + AV.w * w3.y;       \
    ACC.z += AV.x * w0.z + AV.y * w1.z + AV.z * w2.z + AV.w * w3.z;       \
    ACC.w += AV.x * w0.w + AV.y * w1.w + AV.z * w2.w + AV.w * w3.w;
    FMA4(acc0, a0) FMA4(acc1, a1) FMA4(acc2, a2) FMA4(acc3, a3)
#undef FMA4
  }

  const int row0 = rowBase + ty * 4;
  if (row0 + 0 < N) *reinterpret_cast<float4*>(out + (size_t)(row0 + 0) * D + tx * 4) = acc0;
  if (row0 + 1 < N) *reinterpret_cast<float4*>(out + (size_t)(row0 + 1) * D + tx * 4) = acc1;
  if (row0 + 2 < N) *reinterpret_cast<float4*>(out + (size_t)(row0 + 2) * D + tx * 4) = acc2;
  if (row0 + 3 < N) *reinterpret_cast<float4*>(out + (size_t)(row0 + 3) * D + tx * 4) = acc3;
}

// ---------------------------------------------------------------------------
// p1_scatter (radix): prologue derives, from block-major countsB,
//   total[bin] (sweep), binBase[bin] (LDS scan), this block's prefix -> cursor.
// Block 0 publishes binBase[257] for p2. Ordering identical to the old
// SC+bsums scheme -> same pair permutation -> same fp result.
// ---------------------------------------------------------------------------
__global__ __launch_bounds__(256) void p1_scatter_kernel(
    const int* __restrict__ src, const int* __restrict__ dst,
    const float* __restrict__ ew, const int* __restrict__ countsB,
    int* __restrict__ binBaseG, int2* __restrict__ tmp, int E, int epb) {
  __shared__ int s[RB];
  __shared__ int cur[RB];
  const int t = threadIdx.x;
  const int b = blockIdx.x;

  int total = 0, pre = 0;
#pragma unroll 8
  for (int i = 0; i < NB; ++i) {
    const int c = countsB[i * RB + t];   // coalesced across t
    if (i == b) pre = total;             // sum of blocks before b
    total += c;
  }
  s[t] = total;
  __syncthreads();
  for (int off = 1; off < 256; off <<= 1) {
    int x = (t >= off) ? s[t - off] : 0;
    __syncthreads();
    s[t] += x;
    __syncthreads();
  }
  const int binBase = s[t] - total;      // exclusive over bins
  cur[t] = binBase + pre;
  if (b == 0) {
    binBaseG[t] = binBase;
    if (t == 255) binBaseG[256] = s[255];   // == E
  }
  __syncthreads();

  const int base = b * epb;
  const int lim = min(base + epb, E);
  for (int i = base + t; i < lim; i += 256) {
    const int d = dst[i];
    const unsigned sv = (unsigned)src[i];
    const float w = ew[i];
    const int pos = atomicAdd(&cur[d >> 8], 1);   // LDS atomic
    tmp[pos] = make_int2((int)((unsigned)d | (sv << 16)), __float_as_int(w));
  }
}

// ---------------------------------------------------------------------------
// p2 (radix): one block per coarse bucket, counting-sort by dst&255,
// emits (src,w) pairs and offs[] directly. Segment bounds from binBaseG.
// ---------------------------------------------------------------------------
__global__ __launch_bounds__(256) void p2_kernel(
    const int2* __restrict__ tmp, const int* __restrict__ binBaseG,
    int* __restrict__ offs, int2* __restrict__ pairs, int N) {
  __shared__ int h[RB];
  __shared__ int s[RB];
  __shared__ int cur[RB];
  const int t = threadIdx.x;
  const int b = blockIdx.x;
  const int segBeg = binBaseG[b];
  const int segEnd = binBaseG[b + 1];

  h[t] = 0;
  __syncthreads();
  for (int i = segBeg + t; i < segEnd; i += 256)
    atomicAdd(&h[tmp[i].x & 255], 1);
  __syncthreads();

  const int v = h[t];
  s[t] = v;
  __syncthreads();
  for (int off = 1; off < 256; off <<= 1) {
    int x = (t >= off) ? s[t - off] : 0;
    __syncthreads();
    s[t] += x;
    __syncthreads();
  }
  const int excl = s[t] - v;
  cur[t] = segBeg + excl;
  const int node = b * RB + t;
  if (node <= N) offs[node] = segBeg + excl;   // offs[N] lands here too
  __syncthreads();

  for (int i = segBeg + t; i < segEnd; i += 256) {
    const int2 r = tmp[i];
    const int lo = r.x & 255;
    const int pos = atomicAdd(&cur[lo], 1);    // LDS atomic
    pairs[pos] = make_int2((int)(((unsigned)r.x) >> 16), r.y);
  }
}

// ---------------------------------------------------------------------------
// Generic CSR build (N > 65536): hist(+rank) atomics + scan trio + bucket
// ---------------------------------------------------------------------------
__global__ __launch_bounds__(256) void hist_kernel(
    const int* __restrict__ dst, int* __restrict__ deg,
    int* __restrict__ posw, int E) {
  int e = blockIdx.x * 256 + threadIdx.x;
  if (e < E) posw[e] = atomicAdd(&deg[dst[e]], 1);
}

#define SCAN_CHUNK 1024
__global__ __launch_bounds__(256) void scan_part_kernel(
    const int* __restrict__ deg, int* __restrict__ offs,
    int* __restrict__ bsums, int N) {
  __shared__ int s[256];
  const int t = threadIdx.x;
  const int base = blockIdx.x * SCAN_CHUNK + t * 4;
  int v0 = 0, v1 = 0, v2 = 0, v3 = 0;
  if (base + 3 < N) {
    const int4 v = *reinterpret_cast<const int4*>(deg + base);
    v0 = v.x; v1 = v.y; v2 = v.z; v3 = v.w;
  } else {
    if (base + 0 < N) v0 = deg[base + 0];
    if (base + 1 < N) v1 = deg[base + 1];
    if (base + 2 < N) v2 = deg[base + 2];
  }
  const int tsum = v0 + v1 + v2 + v3;
  s[t] = tsum;
  __syncthreads();
  for (int off = 1; off < 256; off <<= 1) {
    int x = (t >= off) ? s[t - off] : 0;
    __syncthreads();
    s[t] += x;
    __syncthreads();
  }
  const int excl = s[t] - tsum;
  if (base + 0 < N) offs[base + 0] = excl;
  if (base + 1 < N) offs[base + 1] = excl + v0;
  if (base + 2 < N) offs[base + 2] = excl + v0 + v1;
  if (base + 3 < N) offs[base + 3] = excl + v0 + v1 + v2;
  if (t == 255) bsums[blockIdx.x] = s[255];
}

__global__ __launch_bounds__(1024) void scan_sums_kernel(
    int* __restrict__ bsums, int* __restrict__ offsN, int nb) {
  __shared__ int s[1024];
  const int t = threadIdx.x;
  const int v = (t < nb) ? bsums[t] : 0;
  s[t] = v;
  __syncthreads();
  for (int off = 1; off < 1024; off <<= 1) {
    int x = (t >= off) ? s[t - off] : 0;
    __syncthreads();
    s[t] += x;
    __syncthreads();
  }
  if (t < nb) bsums[t] = s[t] - v;
  if (t == nb - 1) *offsN = s[t];
}

__global__ __launch_bounds__(256) void scan_add_kernel(
    int* __restrict__ offs, const int* __restrict__ bsums, int N) {
  const int i = blockIdx.x * 256 + threadIdx.x;
  if (i < N) offs[i] += bsums[i >> 10];
}

__global__ __launch_bounds__(256) void bucket_kernel(
    const int* __restrict__ src, const int* __restrict__ dst,
    const float* __restrict__ ew, const int* __restrict__ offs,
    const int* __restrict__ posw, int2* __restrict__ pairs, int E) {
  int e = blockIdx.x * 256 + threadIdx.x;
  if (e < E) {
    const int pos = offs[dst[e]] + posw[e];
    pairs[pos] = make_int2(src[e], __float_as_int(ew[e]));
  }
}

// ---------------------------------------------------------------------------
// FUSED: out[row] = relu(agg(H)[row] + b1) @ W  (gather + gemm2 in one pass)
// ---------------------------------------------------------------------------
__global__ __launch_bounds__(256, 4) void agg_gemm_kernel(
    const float* __restrict__ H, const int* __restrict__ offs,
    const int2* __restrict__ pairs, const float* __restrict__ b1,
    const float* __restrict__ W, float* __restrict__ out, int N) {
  __shared__ float sA[64][68];
  __shared__ float sW[64][68];
  const int t = threadIdx.x;
  const int rowBase = blockIdx.x * 64;

#pragma unroll
  for (int i = t * 4; i < 4096; i += 1024) {
    const int k = i >> 6, c = i & 63;
    *reinterpret_cast<float4*>(&sW[k][c]) =
        *reinterpret_cast<const float4*>(W + i);
  }

  const int l4 = t & 15;
  const int sub = t >> 4;
  const float4 bb = *reinterpret_cast<const float4*>(b1 + l4 * 4);
#pragma unroll
  for (int p = 0; p < 4; ++p) {
    const int r = p * 16 + sub;
    const int node = rowBase + r;
    float4 A0 = make_float4(0.f, 0.f, 0.f, 0.f);
    float4 A1 = make_float4(0.f, 0.f, 0.f, 0.f);
    float4 A2 = make_float4(0.f, 0.f, 0.f, 0.f);
    float4 A3 = make_float4(0.f, 0.f, 0.f, 0.f);
    if (node < N) {
      const int beg = offs[node], end = offs[node + 1];
      int i = beg;
      for (; i + 4 <= end; i += 4) {
        const int2 p0 = pairs[i], p1 = pairs[i + 1], p2 = pairs[i + 2], p3 = pairs[i + 3];
        const float4 v0 = *reinterpret_cast<const float4*>(H + (size_t)p0.x * D + l4 * 4);
        const float4 v1 = *reinterpret_cast<const float4*>(H + (size_t)p1.x * D + l4 * 4);
        const float4 v2 = *reinterpret_cast<const float4*>(H + (size_t)p2.x * D + l4 * 4);
        const float4 v3 = *reinterpret_cast<const float4*>(H + (size_t)p3.x * D + l4 * 4);
        const float w0 = __int_as_float(p0.y), w1 = __int_as_float(p1.y);
        const float w2 = __int_as_float(p2.y), w3 = __int_as_float(p3.y);
        A0.x += w0 * v0.x; A0.y += w0 * v0.y; A0.z += w0 * v0.z; A0.w += w0 * v0.w;
        A1.x += w1 * v1.x; A1.y += w1 * v1.y; A1.z += w1 * v1.z; A1.w += w1 * v1.w;
        A2.x += w2 * v2.x; A2.y += w2 * v2.y; A2.z += w2 * v2.z; A2.w += w2 * v2.w;
        A3.x += w3 * v3.x; A3.y += w3 * v3.y; A3.z += w3 * v3.z; A3.w += w3 * v3.w;
      }
      for (; i < end; ++i) {
        const int2 pp = pairs[i];
        const float4 v = *reinterpret_cast<const float4*>(H + (size_t)pp.x * D + l4 * 4);
        const float w = __int_as_float(pp.y);
        A0.x += w * v.x; A0.y += w * v.y; A0.z += w * v.z; A0.w += w * v.w;
      }
    }
    float4 rr;
    rr.x = fmaxf((A0.x + A1.x) + (A2.x + A3.x) + bb.x, 0.f);
    rr.y = fmaxf((A0.y + A1.y) + (A2.y + A3.y) + bb.y, 0.f);
    rr.z = fmaxf((A0.z + A1.z) + (A2.z + A3.z) + bb.z, 0.f);
    rr.w = fmaxf((A0.w + A1.w) + (A2.w + A3.w) + bb.w, 0.f);
    *reinterpret_cast<float4*>(&sA[r][l4 * 4]) = rr;
  }
  __syncthreads();

  const int ty = t >> 4, tx = t & 15;
  float4 acc0 = make_float4(0.f, 0.f, 0.f, 0.f);
  float4 acc1 = make_float4(0.f, 0.f, 0.f, 0.f);
  float4 acc2 = make_float4(0.f, 0.f, 0.f, 0.f);
  float4 acc3 = make_float4(0.f, 0.f, 0.f, 0.f);

#pragma unroll 4
  for (int kq = 0; kq < 16; ++kq) {
    const float4 w0 = *reinterpret_cast<const float4*>(&sW[kq * 4 + 0][tx * 4]);
    const float4 w1 = *reinterpret_cast<const float4*>(&sW[kq * 4 + 1][tx * 4]);
    const float4 w2 = *reinterpret_cast<const float4*>(&sW[kq * 4 + 2][tx * 4]);
    const float4 w3 = *reinterpret_cast<const float4*>(&sW[kq * 4 + 3][tx * 4]);
    const float4 a0 = *reinterpret_cast<const float4*>(&sA[ty * 4 + 0][kq * 4]);
    const float4 a1 = *reinterpret_cast<const float4*>(&sA[ty * 4 + 1][kq * 4]);
    const float4 a2 = *reinterpret_cast<const float4*>(&sA[ty * 4 + 2][kq * 4]);
    const float4 a3 = *reinterpret_cast<const float4*>(&sA[ty * 4 + 3][kq * 4]);
#define FMA4(ACC, AV)                                                     \
    ACC.x += AV.x * w0.x + AV.y * w1.x + AV.z * w2.x + AV.w * w3.x;       \
    ACC.y += AV.x * w0.y + AV.y * w1.y + AV.z * w2.y + AV.w * w3.y;       \
    ACC.z += AV.x * w0.z + AV.y * w1.z + AV.z * w2.z + AV.w * w3.z;       \
    ACC.w += AV.x * w0.w + AV.y * w1.w + AV.z * w2.w + AV.w * w3.w;
    FMA4(acc0, a0) FMA4(acc1, a1) FMA4(acc2, a2) FMA4(acc3, a3)
#undef FMA4
  }

  const int row0 = rowBase + ty * 4;
  if (row0 + 0 < N) *reinterpret_cast<float4*>(out + (size_t)(row0 + 0) * D + tx * 4) = acc0;
  if (row0 + 1 < N) *reinterpret_cast<float4*>(out + (size_t)(row0 + 1) * D + tx * 4) = acc1;
  if (row0 + 2 < N) *reinterpret_cast<float4*>(out + (size_t)(row0 + 2) * D + tx * 4) = acc2;
  if (row0 + 3 < N) *reinterpret_cast<float4*>(out + (size_t)(row0 + 3) * D + tx * 4) = acc3;
}

// ---------------------------------------------------------------------------
// Gather-aggregate (final layer): 16 lanes/node, float4/lane, 4-deep MLP.
// ---------------------------------------------------------------------------
template <bool BIAS>
__global__ __launch_bounds__(256) void gather_agg_kernel(
    const float* __restrict__ H, const int* __restrict__ offs,
    const int2* __restrict__ pairs,
    const float* __restrict__ bias, float* __restrict__ out, int N) {
  const int l4 = threadIdx.x & 15;
  const int node = blockIdx.x * 16 + (threadIdx.x >> 4);
  if (node >= N) return;
  const int beg = offs[node], end = offs[node + 1];
  float4 A0 = make_float4(0.f, 0.f, 0.f, 0.f);
  float4 A1 = make_float4(0.f, 0.f, 0.f, 0.f);
  float4 A2 = make_float4(0.f, 0.f, 0.f, 0.f);
  float4 A3 = make_float4(0.f, 0.f, 0.f, 0.f);
  int i = beg;
  for (; i + 4 <= end; i += 4) {
    const int2 p0 = pairs[i], p1 = pairs[i + 1], p2 = pairs[i + 2], p3 = pairs[i + 3];
    const float4 v0 = *reinterpret_cast<const float4*>(H + (size_t)p0.x * D + l4 * 4);
    const float4 v1 = *reinterpret_cast<const float4*>(H + (size_t)p1.x * D + l4 * 4);
    const float4 v2 = *reinterpret_cast<const float4*>(H + (size_t)p2.x * D + l4 * 4);
    const float4 v3 = *reinterpret_cast<const float4*>(H + (size_t)p3.x * D + l4 * 4);
    const float w0 = __int_as_float(p0.y), w1 = __int_as_float(p1.y);
    const float w2 = __int_as_float(p2.y), w3 = __int_as_float(p3.y);
    A0.x += w0 * v0.x; A0.y += w0 * v0.y; A0.z += w0 * v0.z; A0.w += w0 * v0.w;
    A1.x += w1 * v1.x; A1.y += w1 * v1.y; A1.z += w1 * v1.z; A1.w += w1 * v1.w;
    A2.x += w2 * v2.x; A2.y += w2 * v2.y; A2.z += w2 * v2.z; A2.w += w2 * v2.w;
    A3.x += w3 * v3.x; A3.y += w3 * v3.y; A3.z += w3 * v3.z; A3.w += w3 * v3.w;
  }
  for (; i < end; ++i) {
    const int2 p = pairs[i];
    const float4 v = *reinterpret_cast<const float4*>(H + (size_t)p.x * D + l4 * 4);
    const float w = __int_as_float(p.y);
    A0.x += w * v.x; A0.y += w * v.y; A0.z += w * v.z; A0.w += w * v.w;
  }
  float4 r;
  r.x = (A0.x + A1.x) + (A2.x + A3.x);
  r.y = (A0.y + A1.y) + (A2.y + A3.y);
  r.z = (A0.z + A1.z) + (A2.z + A3.z);
  r.w = (A0.w + A1.w) + (A2.w + A3.w);
  if (BIAS) {
    const float4 b = *reinterpret_cast<const float4*>(bias + l4 * 4);
    r.x += b.x; r.y += b.y; r.z += b.z; r.w += b.w;
  }
  *reinterpret_cast<float4*>(out + (size_t)node * D + l4 * 4) = r;
}

// ---------------------- fallback (atomic scatter) path ---------------------
__global__ __launch_bounds__(256) void scatter_kernel(
    const float* __restrict__ H, const float* __restrict__ ew,
    const int* __restrict__ src, const int* __restrict__ dst,
    float* __restrict__ out, int nEdges) {
  const int tid = blockIdx.x * 256 + threadIdx.x;
  const int e = tid >> 4;
  if (e >= nEdges) return;
  const int c = (tid & 15) * 4;
  const float w = ew[e];
  const float4 v = *reinterpret_cast<const float4*>(H + (size_t)src[e] * D + c);
  float* o = out + (size_t)dst[e] * D + c;
  atomicAdd(o + 0, w * v.x);
  atomicAdd(o + 1, w * v.y);
  atomicAdd(o + 2, w * v.z);
  atomicAdd(o + 3, w * v.w);
}

__global__ __launch_bounds__(256) void fill_bias_kernel(
    float* __restrict__ out, const float* __restrict__ b, int total) {
  int i = blockIdx.x * 256 + threadIdx.x;
  if (i < total) out[i] = b[i & 63];
}

// ---------------------------------------------------------------------------
extern "C" void kernel_launch(void* const* d_in, const int* in_sizes, int n_in,
                              void* d_out, int out_size, void* d_ws,
                              size_t ws_size, hipStream_t stream) {
  const float* X  = (const float*)d_in[0];
  const float* ew = (const float*)d_in[1];
  const float* W1 = (const float*)d_in[2];
  const float* b1 = (const float*)d_in[3];
  const float* W2 = (const float*)d_in[4];
  const float* b2 = (const float*)d_in[5];
  const int*   ei = (const int*)d_in[6];

  const int N = in_sizes[0] / D;   // 50000
  const int E = in_sizes[6] / 2;   // 800000
  const int* src = ei;
  const int* dst = ei + E;
  float* out = (float*)d_out;

  // workspace layout
  char* ws = (char*)d_ws;
  float* buf0 = (float*)ws;                 ws += (size_t)N * D * 4;
  float* buf1 = (float*)ws;                 ws += (size_t)N * D * 4;
  const size_t baseBytes = (size_t)(ws - (char*)d_ws);
  int2*  pairs    = (int2*)ws;              ws += (size_t)E * 8;
  int*   offs     = (int*)ws;               ws += (size_t)(N + 1) * 4;
  int*   countsB  = (int*)ws;               ws += (size_t)NB * RB * 4;
  int*   binBaseG = (int*)ws;               ws += (size_t)(RB + 1) * 4;
  const size_t needBytes = (size_t)(ws - (char*)d_ws);

  const int gemmBlocks = (N + 63) / 64;
  const int aggBlocks  = (N + 15) / 16;
  const int edgeBlocks = (E + 255) / 256;

  if (ws_size >= needBytes) {
    if (N <= NB * RB && (size_t)N * D * 4 >= (size_t)E * 8) {
      // ---- radix build merged with gemm1: 3 launches, no global atomics ----
      int2* tmp = (int2*)buf1;   // E records (buf1 dead until agg_gemm writes)
      const int epb = (E + NB - 1) / NB;
      hist_gemm_kernel<<<NB + gemmBlocks, 256, 0, stream>>>(
          dst, countsB, E, epb, X, W1, buf0, N);
      p1_scatter_kernel<<<NB, 256, 0, stream>>>(src, dst, ew, countsB,
                                                binBaseG, tmp, E, epb);
      p2_kernel<<<RB, 256, 0, stream>>>(tmp, binBaseG, offs, pairs, N);
    } else {
      // ---- generic build + separate gemm1 ----
      int* deg   = (int*)buf0;
      int* bsums = (int*)buf0 + N;
      int* posw  = (int*)buf1;
      const int nb = (N + SCAN_CHUNK - 1) / SCAN_CHUNK;
      hipMemsetAsync(deg, 0, (size_t)N * 4, stream);
      hist_kernel<<<edgeBlocks, 256, 0, stream>>>(dst, deg, posw, E);
      scan_part_kernel<<<nb, 256, 0, stream>>>(deg, offs, bsums, N);
      scan_sums_kernel<<<1, 1024, 0, stream>>>(bsums, offs + N, nb);
      scan_add_kernel<<<(N + 255) / 256, 256, 0, stream>>>(offs, bsums, N);
      bucket_kernel<<<edgeBlocks, 256, 0, stream>>>(src, dst, ew, offs, posw, pairs, E);
      gemm64_kernel<false><<<gemmBlocks, 256, 0, stream>>>(X, W1, nullptr, buf0, N);
    }

    // ---- fused(agg+relu+gemm2) -> final agg ----
    agg_gemm_kernel<<<gemmBlocks, 256, 0, stream>>>(buf0, offs, pairs, b1, W2, buf1, N);
    gather_agg_kernel<true><<<aggBlocks, 256, 0, stream>>>(buf1, offs, pairs, b2, out, N);
  } else if (ws_size >= baseBytes) {
    // ---- fallback: atomic scatter (slow but correct) ----
    const int scatBlocks = (E * 16 + 255) / 256;
    const int fillBlocks = (N * D + 255) / 256;
    gemm64_kernel<false><<<gemmBlocks, 256, 0, stream>>>(X, W1, nullptr, buf0, N);
    hipMemsetAsync(buf1, 0, (size_t)N * D * 4, stream);
    scatter_kernel<<<scatBlocks, 256, 0, stream>>>(buf0, ew, src, dst, buf1, E);
    gemm64_kernel<true><<<gemmBlocks, 256, 0, stream>>>(buf1, W2, b1, buf0, N);
    fill_bias_kernel<<<fillBlocks, 256, 0, stream>>>(out, b2, N * D);
    scatter_kernel<<<scatBlocks, 256, 0, stream>>>(buf0, ew, src, dst, out, E);
  }
}